// Round 15
// baseline (154.269 us; speedup 1.0000x reference)
//
#include <hip/hip_runtime.h>

typedef __attribute__((ext_vector_type(8))) short bf16x8;
typedef __attribute__((ext_vector_type(4))) float f32x4;

__device__ __forceinline__ float gelu_fast(float x) {
    const float u = 0.7978845608028654f * x * (1.0f + 0.044715f * x * x);
    return x * __builtin_amdgcn_rcpf(1.0f + __expf(-2.0f * u));
}

__device__ __forceinline__ unsigned short f2bf(float x) {
    union { float f; unsigned int u; } v; v.f = x;
    unsigned int r = v.u + 0x7FFF + ((v.u >> 16) & 1);
    return (unsigned short)(r >> 16);
}

// blocks [0,256): Gf production (fragment-major, spec's B-loads coalesce).
// blocks [256,260): weight transposes.
__global__ __launch_bounds__(256) void init_kernel(const float* __restrict__ phi_r, const float* __restrict__ mp_r,
                                                   const float* __restrict__ mm_r, unsigned short* __restrict__ GcR,
                                                   const float* __restrict__ phi_c, const float* __restrict__ mp_c,
                                                   const float* __restrict__ mm_c, unsigned short* __restrict__ GcC,
                                                   const float* __restrict__ w1r, const float* __restrict__ w1c,
                                                   const float* __restrict__ w2r, const float* __restrict__ w2c,
                                                   unsigned short* __restrict__ w1tr, unsigned short* __restrict__ w1tc,
                                                   unsigned short* __restrict__ w2tr, unsigned short* __restrict__ w2tc) {
    const int bid = blockIdx.x, tid = threadIdx.x;
    __shared__ float phis[256];
    __shared__ unsigned short tile[4096];  // 16 s x 256 (e-major, d-minor)
    if (bid < 256) {
        const int side = bid >> 7, rem = bid & 127;
        const int chunk = rem >> 3, s0 = (rem & 7) * 16;
        const float* phi = side ? phi_c : phi_r;
        const float* mp  = side ? mp_c  : mp_r;
        const float* mm  = side ? mm_c  : mm_r;
        unsigned short* Gct = side ? GcC : GcR;
        const int i = chunk * 256 + tid;
        float pe[16], po[16];
#pragma unroll
        for (int k = 0; k < 16; ++k) {
            const float a = mp[k * 4096 + i];
            const float b = mm[k * 4096 + i];
            pe[k] = a + b; po[k] = a - b;
        }
        phis[tid] = phi[s0 * 16 + tid];
        __syncthreads();
        const int e = tid & 63, dl = tid >> 6;
        const int d0 = chunk * 4;
        const int kk = d0 >> 5, g3 = (d0 >> 3) & 3, jl0 = d0 & 7;
#pragma unroll
        for (int sb = 0; sb < 16; ++sb) {
            const int s = s0 + sb;
            const float* pk = &phis[sb * 16];
            float acc = 0.0f;
            if (s & 1) {
#pragma unroll
                for (int k = 0; k < 16; ++k) acc += pk[k] * po[k];
            } else {
#pragma unroll
                for (int k = 0; k < 16; ++k) acc += pk[k] * pe[k];
            }
            tile[sb * 256 + e * 4 + dl] = f2bf(acc);
        }
        __syncthreads();
#pragma unroll
        for (int it = 0; it < 4; ++it) {
            const int p = it * 256 + tid;
            const int sb = p >> 6, ee = p & 63;
            uint2 v = *(const uint2*)&tile[sb * 256 + ee * 4];
            *(uint2*)&Gct[(size_t)(s0 + sb) * 4096 + (((ee >> 4) << 1) + kk) * 512 +
                          (g3 * 16 + (ee & 15)) * 8 + jl0] = v;
        }
    } else {
        const int b = bid - 256;
        if (b < 2) {
            const float* w1 = b ? w1c : w1r;
            unsigned short* dst = b ? w1tc : w1tr;
            const int n = tid;
            for (int k = 0; k < 64; ++k) dst[n * 64 + k] = f2bf(w1[k * 256 + n]);
        } else {
            const float* w2 = (b == 3) ? w2c : w2r;
            unsigned short* dst = (b == 3) ? w2tc : w2tr;
            const int n = tid & 63, kq = tid >> 6;
            for (int kk2 = 0; kk2 < 64; ++kk2) {
                const int k = kq * 64 + kk2;
                dst[n * 256 + k] = f2bf(w2[k * 64 + n]);
            }
        }
    }
}

// Kernel S: LN + e-split spec. Block = (seq, eh): eh owns output cols [32eh, 32eh+32).
// grid 1024, 256 thr, 34 KB LDS. acc[8][2] (64 AGPR) + Ba/Bb[4] -> spec peak ~126 regs,
// so (256,3) is SAFE (cap ~170; R10's spill was cap 85 vs need 250). 12-16 waves/CU.
// B-fragments for eh are CONTIGUOUS in Gf (frag 4eh..4eh+4) -> coalesced, no dup traffic.
// LDS bytes: ys [0,18432) | scrA [18432,26624) scrB [26624,34816).
#define SPEC_BODY_H(RR, BC, BN)                                                      \
    {                                                                                \
        const int s_ = 4 * (RR) + w;                                                 \
        if ((RR) < 31) {                                                             \
            const unsigned short* gq = Gf + (size_t)(s_ + 4) * 4096 + eh * 2048 + lane * 8; \
            _Pragma("unroll")                                                        \
            for (int f = 0; f < 4; ++f) BN[f] = *(const bf16x8*)(gq + f * 512);      \
        }                                                                            \
        const int jmin_ = __builtin_amdgcn_readfirstlane(s_ >> 4);                   \
        _Pragma("unroll")                                                            \
        for (int j = 0; j < 8; ++j) {                                                \
            if (j >= jmin_) {                                                        \
                const int row_ = 16 + 16 * j - s_ + m;                               \
                const int c0_ = (g ^ (row_ & 7)) << 3;                               \
                const int ab_ = row_ * 64;                                           \
                bf16x8 a0_ = *(const bf16x8*)&lds[ab_ + c0_];                        \
                bf16x8 a1_ = *(const bf16x8*)&lds[ab_ + (c0_ ^ 32)];                 \
                _Pragma("unroll")                                                    \
                for (int nt = 0; nt < 2; ++nt) {                                     \
                    acc[j][nt] = __builtin_amdgcn_mfma_f32_16x16x32_bf16(a0_, BC[2 * nt], acc[j][nt], 0, 0, 0);     \
                    acc[j][nt] = __builtin_amdgcn_mfma_f32_16x16x32_bf16(a1_, BC[2 * nt + 1], acc[j][nt], 0, 0, 0); \
                }                                                                    \
            }                                                                        \
        }                                                                            \
    }

__global__ __launch_bounds__(256, 3) void spec_kernel(const float* __restrict__ xin,
                                                      unsigned short* __restrict__ spcb,
                                                      const unsigned short* __restrict__ Gf,
                                                      const float* __restrict__ gamma,
                                                      const float* __restrict__ beta,
                                                      int rmul, int tmul) {
    __shared__ unsigned short lds[17408];  // 34 KB
    const int tid = threadIdx.x;
    const int w = tid >> 6, lane = tid & 63;
    const int seq = blockIdx.x >> 1, eh = blockIdx.x & 1;
    const int m = lane & 15, g = lane >> 4;
    const int bb = seq >> 7, rr = seq & 127;
    const size_t base = (size_t)bb * 1048576 + (size_t)rr * (size_t)rmul;

    // zero ys prefix rows 0..15 (bytes [0,2048))
    {
        uint2 z; z.x = 0u; z.y = 0u;
        *(uint2*)((char*)lds + tid * 8) = z;
    }

    // round-0 B prefetch (L2 latency hides under LN)
    bf16x8 Ba[4], Bb[4];
    {
        const unsigned short* gq = Gf + (size_t)w * 4096 + eh * 2048 + lane * 8;
#pragma unroll
        for (int f = 0; f < 4; ++f) Ba[f] = *(const bf16x8*)(gq + f * 512);
    }

    // ---- LN rows w*32..w*32+31 into swizzled ys ----
    {
        const float gl = gamma[lane], bl = beta[lane];
        float xv[32];
#pragma unroll
        for (int ti = 0; ti < 32; ++ti)
            xv[ti] = xin[base + (size_t)(w * 32 + ti) * tmul + lane];
#pragma unroll
        for (int ti = 0; ti < 32; ++ti) {
            const int t = w * 32 + ti;
            float s1 = xv[ti];
#pragma unroll
            for (int mk = 32; mk >= 1; mk >>= 1) s1 += __shfl_xor(s1, mk);
            const float mu = s1 * (1.0f / 64.0f);
            const float dv = xv[ti] - mu;
            float s2 = dv * dv;
#pragma unroll
            for (int mk = 32; mk >= 1; mk >>= 1) s2 += __shfl_xor(s2, mk);
            const float rstd = rsqrtf(s2 * (1.0f / 64.0f) + 1e-5f);
            const float nv = dv * rstd * gl + bl;
            lds[(t + 16) * 64 + (((lane >> 3) ^ (t & 7)) << 3) + (lane & 7)] = f2bf(nv);
        }
    }
    __syncthreads();  // ys ready

    // ---- spec loop (no barriers) ----
    f32x4 acc[8][2];
#pragma unroll
    for (int j = 0; j < 8; ++j)
#pragma unroll
        for (int nt = 0; nt < 2; ++nt) {
            f32x4 z = {0.0f, 0.0f, 0.0f, 0.0f};
            acc[j][nt] = z;
        }
    for (int rp = 0; rp < 16; ++rp) {
        SPEC_BODY_H(2 * rp,     Ba, Bb);
        SPEC_BODY_H(2 * rp + 1, Bb, Ba);
    }

    // ---- reduction over s-residues (w0 += w1, w2 += w3, then w0 += w2) ----
    char* const scrA = (char*)lds + 18432;  // 8 KB
    char* const scrB = (char*)lds + 26624;  // 8 KB
    // P1: j0-3
    if (w == 1 || w == 3) {
        char* pb = (w == 1 ? scrA : scrB) + lane * 16;
#pragma unroll
        for (int j = 0; j < 4; ++j)
#pragma unroll
            for (int nt = 0; nt < 2; ++nt)
                *(f32x4*)(pb + (j * 2 + nt) * 1024) = acc[j][nt];
    }
    __syncthreads();
    if (w == 0 || w == 2) {
        const char* pb = (w == 0 ? scrA : scrB) + lane * 16;
#pragma unroll
        for (int j = 0; j < 4; ++j)
#pragma unroll
            for (int nt = 0; nt < 2; ++nt)
                acc[j][nt] += *(const f32x4*)(pb + (j * 2 + nt) * 1024);
    }
    __syncthreads();
    // P2: j4-7
    if (w == 1 || w == 3) {
        char* pb = (w == 1 ? scrA : scrB) + lane * 16;
#pragma unroll
        for (int j = 4; j < 8; ++j)
#pragma unroll
            for (int nt = 0; nt < 2; ++nt)
                *(f32x4*)(pb + ((j - 4) * 2 + nt) * 1024) = acc[j][nt];
    }
    __syncthreads();
    if (w == 0 || w == 2) {
        const char* pb = (w == 0 ? scrA : scrB) + lane * 16;
#pragma unroll
        for (int j = 4; j < 8; ++j)
#pragma unroll
            for (int nt = 0; nt < 2; ++nt)
                acc[j][nt] += *(const f32x4*)(pb + ((j - 4) * 2 + nt) * 1024);
    }
    __syncthreads();
    // P3: w2 dumps full (j0-3 -> scrA, j4-7 -> scrB); w0 sums and stores X-half
    if (w == 2) {
#pragma unroll
        for (int j = 0; j < 4; ++j)
#pragma unroll
            for (int nt = 0; nt < 2; ++nt) {
                *(f32x4*)(scrA + (j * 2 + nt) * 1024 + lane * 16) = acc[j][nt];
                *(f32x4*)(scrB + (j * 2 + nt) * 1024 + lane * 16) = acc[j + 4][nt];
            }
    }
    __syncthreads();
    if (w == 0) {
        unsigned short* sp0 = spcb + (size_t)seq * 8192;
#pragma unroll
        for (int j = 0; j < 8; ++j)
#pragma unroll
            for (int nt = 0; nt < 2; ++nt) {
                const char* src = (j < 4 ? scrA : scrB) + ((j & 3) * 2 + nt) * 1024 + lane * 16;
                acc[j][nt] += *(const f32x4*)src;
                const int col = (2 * eh + nt) * 16 + m;
                const int c = col >> 3;
#pragma unroll
                for (int rv = 0; rv < 4; ++rv) {
                    const int row = j * 16 + 4 * g + rv;
                    sp0[row * 64 + ((c ^ (row & 7)) << 3) + (col & 7)] = f2bf(acc[j][nt][rv]);
                }
            }
    }
}

// Kernel M: MLP + residual. X via global_load_lds (pre-swizzled), full H in LDS.
// LDS ush: X [0,8192), H [8192,40960) -> 80 KB, grid 512, 2 blocks/CU.
__global__ __launch_bounds__(256, 2) void mlp_kernel(const unsigned short* __restrict__ spcb,
                                                     const unsigned short* __restrict__ w1t,
                                                     const unsigned short* __restrict__ w2t,
                                                     const float* __restrict__ b1,
                                                     const float* __restrict__ b2,
                                                     const float* __restrict__ xin,
                                                     float* __restrict__ xout,
                                                     int rmul, int tmul) {
    __shared__ unsigned short mld[40960];
    const int seq = blockIdx.x, tid = threadIdx.x;
    const int w = tid >> 6, lane = tid & 63;
    const int m = lane & 15, g = lane >> 4;
    const int bb = seq >> 7, rr = seq & 127;
    const size_t base = (size_t)bb * 1048576 + (size_t)rr * (size_t)rmul;

    {
        const char* xsrc = (const char*)spcb + (size_t)seq * 16384 + w * 1024 + lane * 16;
#pragma unroll
        for (int i = 0; i < 4; ++i)
            __builtin_amdgcn_global_load_lds((const void*)(xsrc + i * 4096),
                                             (void*)&mld[i * 2048 + w * 512], 16, 0, 0);
    }
    // residual prefetch (overlaps X staging + weight loads)
    float xr[2][4][4];
#pragma unroll
    for (int mt = 0; mt < 2; ++mt)
#pragma unroll
        for (int nt = 0; nt < 4; ++nt)
#pragma unroll
            for (int rv = 0; rv < 4; ++rv)
                xr[mt][nt][rv] = xin[base + (size_t)((w + 4 * mt) * 16 + 4 * g + rv) * tmul + nt * 16 + m];
    // W1 fragments (wave owns hidden cols [64w, 64w+64))
    bf16x8 bw1[4][2];
    float b1v[4];
#pragma unroll
    for (int nt = 0; nt < 4; ++nt) {
        const int row = w * 64 + nt * 16 + m;
#pragma unroll
        for (int j = 0; j < 2; ++j)
            bw1[nt][j] = *(const bf16x8*)&w1t[row * 64 + (4 * j + g) * 8];
        b1v[nt] = b1[w * 64 + nt * 16 + m];
    }
    __syncthreads();  // X staged

    // GEMM1: H = gelu(X @ W1 + b1)
    f32x4 acc1[8][4];
#pragma unroll
    for (int mt = 0; mt < 8; ++mt)
#pragma unroll
        for (int nt = 0; nt < 4; ++nt) {
            f32x4 z = {b1v[nt], b1v[nt], b1v[nt], b1v[nt]};
            acc1[mt][nt] = z;
        }
#pragma unroll
    for (int mt = 0; mt < 8; ++mt) {
        const int row = mt * 16 + m;
        const int c0 = (g ^ (row & 7)) << 3;
        bf16x8 a0 = *(const bf16x8*)&mld[row * 64 + c0];
        bf16x8 a1 = *(const bf16x8*)&mld[row * 64 + (c0 ^ 32)];
#pragma unroll
        for (int nt = 0; nt < 4; ++nt) {
            acc1[mt][nt] = __builtin_amdgcn_mfma_f32_16x16x32_bf16(a0, bw1[nt][0], acc1[mt][nt], 0, 0, 0);
            acc1[mt][nt] = __builtin_amdgcn_mfma_f32_16x16x32_bf16(a1, bw1[nt][1], acc1[mt][nt], 0, 0, 0);
        }
    }
    // gelu + H bf16 to LDS (swizzled, row stride 256 ush)
#pragma unroll
    for (int mt = 0; mt < 8; ++mt)
#pragma unroll
        for (int nt = 0; nt < 4; ++nt) {
            const int col = w * 64 + nt * 16 + m;
            const int c = col >> 3, jj = col & 7;
#pragma unroll
            for (int rv = 0; rv < 4; ++rv) {
                const int row = mt * 16 + 4 * g + rv;
                mld[8192 + row * 256 + ((c ^ (row & 7)) << 3) + jj] = f2bf(gelu_fast(acc1[mt][nt][rv]));
            }
        }
    __syncthreads();  // H complete

    // GEMM2: O = H @ W2 + b2 + xin
    float b2v[4];
#pragma unroll
    for (int nt = 0; nt < 4; ++nt) b2v[nt] = b2[nt * 16 + m];
    f32x4 acc2[2][4];
#pragma unroll
    for (int mt = 0; mt < 2; ++mt)
#pragma unroll
        for (int nt = 0; nt < 4; ++nt) {
            f32x4 z = {b2v[nt], b2v[nt], b2v[nt], b2v[nt]};
            acc2[mt][nt] = z;
        }
#pragma unroll
    for (int j = 0; j < 8; ++j) {
        bf16x8 aa[2];
#pragma unroll
        for (int mt = 0; mt < 2; ++mt) {
            const int row = (w + 4 * mt) * 16 + m;
            aa[mt] = *(const bf16x8*)&mld[8192 + row * 256 + (((4 * j + g) ^ (row & 7)) << 3)];
        }
#pragma unroll
        for (int nt = 0; nt < 4; ++nt) {
            const int row = nt * 16 + m;
            bf16x8 bfr = *(const bf16x8*)&w2t[row * 256 + (4 * j + g) * 8];
            acc2[0][nt] = __builtin_amdgcn_mfma_f32_16x16x32_bf16(aa[0], bfr, acc2[0][nt], 0, 0, 0);
            acc2[1][nt] = __builtin_amdgcn_mfma_f32_16x16x32_bf16(aa[1], bfr, acc2[1][nt], 0, 0, 0);
        }
    }
#pragma unroll
    for (int mt = 0; mt < 2; ++mt)
#pragma unroll
        for (int nt = 0; nt < 4; ++nt)
#pragma unroll
            for (int rv = 0; rv < 4; ++rv) {
                const int row = (w + 4 * mt) * 16 + 4 * g + rv;
                const int col = nt * 16 + m;
                const size_t xi = base + (size_t)row * tmul + col;
                xout[xi] = xr[mt][nt][rv] + acc2[mt][nt][rv];
            }
}

extern "C" void kernel_launch(void* const* d_in, const int* in_sizes, int n_in,
                              void* d_out, int out_size, void* d_ws, size_t ws_size,
                              hipStream_t stream) {
    const float* v         = (const float*)d_in[0];
    const float* gamma_row = (const float*)d_in[1];
    const float* beta_row  = (const float*)d_in[2];
    const float* gamma_col = (const float*)d_in[3];
    const float* beta_col  = (const float*)d_in[4];
    const float* mp_row    = (const float*)d_in[5];
    const float* mm_row    = (const float*)d_in[6];
    const float* mp_col    = (const float*)d_in[7];
    const float* mm_col    = (const float*)d_in[8];
    const float* w1_row    = (const float*)d_in[9];
    const float* b1_row    = (const float*)d_in[10];
    const float* w2_row    = (const float*)d_in[11];
    const float* b2_row    = (const float*)d_in[12];
    const float* w1_col    = (const float*)d_in[13];
    const float* b1_col    = (const float*)d_in[14];
    const float* w2_col    = (const float*)d_in[15];
    const float* b2_col    = (const float*)d_in[16];
    const float* phi_row   = (const float*)d_in[17];
    const float* phi_col   = (const float*)d_in[18];
    float* out = (float*)d_out;
    char* ws   = (char*)d_ws;

    unsigned short* GfR  = (unsigned short*)ws;                      // 1 MB
    unsigned short* GfC  = (unsigned short*)(ws + (1u << 20));       // 1 MB
    unsigned short* w1tR = (unsigned short*)(ws + (2u << 20));
    unsigned short* w2tR = (unsigned short*)(ws + (2u << 20) + 32768);
    unsigned short* w1tC = (unsigned short*)(ws + (2u << 20) + 65536);
    unsigned short* w2tC = (unsigned short*)(ws + (2u << 20) + 98304);
    unsigned short* spcb = (unsigned short*)(ws + (3u << 20));       // 8 MB

    init_kernel<<<260, 256, 0, stream>>>(phi_row, mp_row, mm_row, GfR,
                                         phi_col, mp_col, mm_col, GfC,
                                         w1_row, w1_col, w2_row, w2_col,
                                         w1tR, w1tC, w2tR, w2tC);

    // row pass: seq=(b,h), rmul=8192 (h stride), tmul=64 (w stride)
    spec_kernel<<<1024, 256, 0, stream>>>(v, spcb, GfR, gamma_row, beta_row, 8192, 64);
    mlp_kernel<<<512, 256, 0, stream>>>(spcb, w1tR, w2tR, b1_row, b2_row, v, out, 8192, 64);

    // col pass: seq=(b,w), rmul=64 (w stride), tmul=8192 (h stride)
    spec_kernel<<<1024, 256, 0, stream>>>(out, spcb, GfC, gamma_col, beta_col, 64, 8192);
    mlp_kernel<<<512, 256, 0, stream>>>(spcb, w1tC, w2tC, b1_col, b2_col, out, out, 64, 8192);
}

// Round 16
// 143.694 us; speedup vs baseline: 1.0736x; 1.0736x over previous
//
#include <hip/hip_runtime.h>

typedef __attribute__((ext_vector_type(8))) short bf16x8;
typedef __attribute__((ext_vector_type(4))) float f32x4;

__device__ __forceinline__ float gelu_fast(float x) {
    const float u = 0.7978845608028654f * x * (1.0f + 0.044715f * x * x);
    return x * __builtin_amdgcn_rcpf(1.0f + __expf(-2.0f * u));
}

__device__ __forceinline__ unsigned short f2bf(float x) {
    union { float f; unsigned int u; } v; v.f = x;
    unsigned int r = v.u + 0x7FFF + ((v.u >> 16) & 1);
    return (unsigned short)(r >> 16);
}

// blocks [0,256): Gf production (fragment-major). blocks [256,260): weight transposes.
__global__ __launch_bounds__(256) void init_kernel(const float* __restrict__ phi_r, const float* __restrict__ mp_r,
                                                   const float* __restrict__ mm_r, unsigned short* __restrict__ GcR,
                                                   const float* __restrict__ phi_c, const float* __restrict__ mp_c,
                                                   const float* __restrict__ mm_c, unsigned short* __restrict__ GcC,
                                                   const float* __restrict__ w1r, const float* __restrict__ w1c,
                                                   const float* __restrict__ w2r, const float* __restrict__ w2c,
                                                   unsigned short* __restrict__ w1tr, unsigned short* __restrict__ w1tc,
                                                   unsigned short* __restrict__ w2tr, unsigned short* __restrict__ w2tc) {
    const int bid = blockIdx.x, tid = threadIdx.x;
    __shared__ float phis[256];
    __shared__ unsigned short tile[4096];
    if (bid < 256) {
        const int side = bid >> 7, rem = bid & 127;
        const int chunk = rem >> 3, s0 = (rem & 7) * 16;
        const float* phi = side ? phi_c : phi_r;
        const float* mp  = side ? mp_c  : mp_r;
        const float* mm  = side ? mm_c  : mm_r;
        unsigned short* Gct = side ? GcC : GcR;
        const int i = chunk * 256 + tid;
        float pe[16], po[16];
#pragma unroll
        for (int k = 0; k < 16; ++k) {
            const float a = mp[k * 4096 + i];
            const float b = mm[k * 4096 + i];
            pe[k] = a + b; po[k] = a - b;
        }
        phis[tid] = phi[s0 * 16 + tid];
        __syncthreads();
        const int e = tid & 63, dl = tid >> 6;
        const int d0 = chunk * 4;
        const int kk = d0 >> 5, g3 = (d0 >> 3) & 3, jl0 = d0 & 7;
#pragma unroll
        for (int sb = 0; sb < 16; ++sb) {
            const int s = s0 + sb;
            const float* pk = &phis[sb * 16];
            float acc = 0.0f;
            if (s & 1) {
#pragma unroll
                for (int k = 0; k < 16; ++k) acc += pk[k] * po[k];
            } else {
#pragma unroll
                for (int k = 0; k < 16; ++k) acc += pk[k] * pe[k];
            }
            tile[sb * 256 + e * 4 + dl] = f2bf(acc);
        }
        __syncthreads();
#pragma unroll
        for (int it = 0; it < 4; ++it) {
            const int p = it * 256 + tid;
            const int sb = p >> 6, ee = p & 63;
            uint2 v = *(const uint2*)&tile[sb * 256 + ee * 4];
            *(uint2*)&Gct[(size_t)(s0 + sb) * 4096 + (((ee >> 4) << 1) + kk) * 512 +
                          (g3 * 16 + (ee & 15)) * 8 + jl0] = v;
        }
    } else {
        const int b = bid - 256;
        if (b < 2) {
            const float* w1 = b ? w1c : w1r;
            unsigned short* dst = b ? w1tc : w1tr;
            const int n = tid;
            for (int k = 0; k < 64; ++k) dst[n * 64 + k] = f2bf(w1[k * 256 + n]);
        } else {
            const float* w2 = (b == 3) ? w2c : w2r;
            unsigned short* dst = (b == 3) ? w2tc : w2tr;
            const int n = tid & 63, kq = tid >> 6;
            for (int kk2 = 0; kk2 < 64; ++kk2) {
                const int k = kq * 64 + kk2;
                dst[n * 256 + k] = f2bf(w2[k * 64 + n]);
            }
        }
    }
}

// Fused pass, 2 seqs/block: 512 thr = 8 waves = 2 seq-groups x 4. Per-wave code identical
// to R14 (acc[8][4]+Ba/Bb double-buffer, ~252 regs/wave at 2 waves/SIMD). Twin waves
// (same s-residue, other seq) issue IDENTICAL Gf addresses concurrently -> L1 absorbs,
// halving per-CU L2 stream. grid 256 = 1 block/CU. 100 KB LDS.
// REGISTER LEDGER: spec peak ~252/wave (saturated, add NOTHING); xr prefetch only
// after acc dies (post-T6). __launch_bounds__ min-waves stays 2 (R10: 3 spills acc).
// LDS bytes (time-shared):
//   ys(sl)   [sl*18432, +18432)                    LN + spec
//   scrA(sl) [36864+sl*32768, +16384), scrB +16384 reduction
//   X(sl)    [sl*16384, +16384)                    after reduction (over ys)
//   H(sl)    [36864+sl*32768, +32768)              GEMM1 out (over scr)
#define SPEC_BODY(RR, BC, BN)                                                        \
    {                                                                                \
        const int s_ = 4 * (RR) + wg;                                                \
        if ((RR) < 31) {                                                             \
            const unsigned short* gq = Gf + (size_t)(s_ + 4) * 4096 + lane * 8;      \
            _Pragma("unroll")                                                        \
            for (int f = 0; f < 8; ++f) BN[f] = *(const bf16x8*)(gq + f * 512);      \
        }                                                                            \
        const int jmin_ = __builtin_amdgcn_readfirstlane(s_ >> 4);                   \
        _Pragma("unroll")                                                            \
        for (int j = 0; j < 8; ++j) {                                                \
            if (j >= jmin_) {                                                        \
                const int row_ = 16 + 16 * j - s_ + m;                               \
                const int c0_ = (g ^ (row_ & 7)) << 3;                               \
                const int ab_ = ysb + row_ * 64;                                     \
                bf16x8 a0_ = *(const bf16x8*)&lds[ab_ + c0_];                        \
                bf16x8 a1_ = *(const bf16x8*)&lds[ab_ + (c0_ ^ 32)];                 \
                _Pragma("unroll")                                                    \
                for (int nt = 0; nt < 4; ++nt) {                                     \
                    acc[j][nt] = __builtin_amdgcn_mfma_f32_16x16x32_bf16(a0_, BC[2 * nt], acc[j][nt], 0, 0, 0);     \
                    acc[j][nt] = __builtin_amdgcn_mfma_f32_16x16x32_bf16(a1_, BC[2 * nt + 1], acc[j][nt], 0, 0, 0); \
                }                                                                    \
            }                                                                        \
        }                                                                            \
    }

__global__ __launch_bounds__(512, 2) void fused_kernel(const float* __restrict__ xin,
                                                       float* __restrict__ xout,
                                                       const unsigned short* __restrict__ Gf,
                                                       const unsigned short* __restrict__ w1t,
                                                       const unsigned short* __restrict__ w2t,
                                                       const float* __restrict__ b1,
                                                       const float* __restrict__ b2,
                                                       const float* __restrict__ gamma,
                                                       const float* __restrict__ beta,
                                                       int rmul, int tmul) {
    __shared__ unsigned short lds[51200];  // 100 KB
    const int tid = threadIdx.x;
    const int w = tid >> 6, lane = tid & 63;
    const int sl = w >> 2, wg = w & 3;
    const int seq = blockIdx.x * 2 + sl;
    const int m = lane & 15, g = lane >> 4;
    const int bb = seq >> 7, rr = seq & 127;
    const size_t base = (size_t)bb * 1048576 + (size_t)rr * (size_t)rmul;
    const int ysb = sl * 9216;                    // ush offset of this seq's ys

    // zero ys prefix rows 0..15 of BOTH regions (2 x 2048 B; 512 thr x 8 B)
    {
        uint2 z; z.x = 0u; z.y = 0u;
        *(uint2*)((char*)lds + (tid >> 8) * 18432 + (tid & 255) * 8) = z;
    }

    // spec round-0 B prefetch (twin waves issue same addresses -> L1 hit)
    bf16x8 Ba[8], Bb[8];
    {
        const unsigned short* gq = Gf + (size_t)wg * 4096 + lane * 8;
#pragma unroll
        for (int f = 0; f < 8; ++f) Ba[f] = *(const bf16x8*)(gq + f * 512);
    }

    // ---- Phase 0: LayerNorm rows wg*32 .. wg*32+31 of seq into swizzled ys ----
    {
        const float gl = gamma[lane], bl = beta[lane];
        float xv[32];
#pragma unroll
        for (int ti = 0; ti < 32; ++ti)
            xv[ti] = xin[base + (size_t)(wg * 32 + ti) * tmul + lane];
#pragma unroll
        for (int ti = 0; ti < 32; ++ti) {
            const int t = wg * 32 + ti;
            float s1 = xv[ti];
#pragma unroll
            for (int mm2 = 32; mm2 >= 1; mm2 >>= 1) s1 += __shfl_xor(s1, mm2);
            const float mu = s1 * (1.0f / 64.0f);
            const float dv = xv[ti] - mu;
            float s2 = dv * dv;
#pragma unroll
            for (int mm2 = 32; mm2 >= 1; mm2 >>= 1) s2 += __shfl_xor(s2, mm2);
            const float rstd = rsqrtf(s2 * (1.0f / 64.0f) + 1e-5f);
            const float nv = dv * rstd * gl + bl;
            lds[ysb + (t + 16) * 64 + (((lane >> 3) ^ (t & 7)) << 3) + (lane & 7)] = f2bf(nv);
        }
    }
    __syncthreads();  // both ys complete

    // ---- Phase 1: spec main loop (no barriers) ----
    f32x4 acc[8][4];
#pragma unroll
    for (int j = 0; j < 8; ++j)
#pragma unroll
        for (int nt = 0; nt < 4; ++nt) {
            f32x4 z = {0.0f, 0.0f, 0.0f, 0.0f};
            acc[j][nt] = z;
        }
    for (int rp = 0; rp < 16; ++rp) {
        SPEC_BODY(2 * rp,     Ba, Bb);
        SPEC_BODY(2 * rp + 1, Bb, Ba);
    }

    // ---- Phase 2: per-group pairwise tree reduction ----
    char* const scrA = (char*)lds + 36864 + sl * 32768;
    char* const scrB = scrA + 16384;
    // T1: wg1 -> scrA (j0-3), wg3 -> scrB (j0-3)
    if (wg == 1 || wg == 3) {
        char* pb = (wg == 1 ? scrA : scrB) + lane * 16;
#pragma unroll
        for (int j = 0; j < 4; ++j)
#pragma unroll
            for (int nt = 0; nt < 4; ++nt)
                *(f32x4*)(pb + (j * 4 + nt) * 1024) = acc[j][nt];
    }
    // weight fragments (overlap reduction); wave owns hidden cols [32wg,32wg+32) per half
    bf16x8 bw1a[2][2], bw1b[2][2];
    float b1va[2], b1vb[2];
#pragma unroll
    for (int nt = 0; nt < 2; ++nt) {
        const int col0 = wg * 32 + nt * 16 + m;
#pragma unroll
        for (int j = 0; j < 2; ++j) {
            bw1a[nt][j] = *(const bf16x8*)&w1t[col0 * 64 + (4 * j + g) * 8];
            bw1b[nt][j] = *(const bf16x8*)&w1t[(128 + col0) * 64 + (4 * j + g) * 8];
        }
        b1va[nt] = b1[col0];
        b1vb[nt] = b1[128 + col0];
    }
    __syncthreads();
    // T2: wg0 += scrA, wg2 += scrB (j0-3)
    if (wg == 0 || wg == 2) {
        const char* pb = (wg == 0 ? scrA : scrB) + lane * 16;
#pragma unroll
        for (int j = 0; j < 4; ++j)
#pragma unroll
            for (int nt = 0; nt < 4; ++nt)
                acc[j][nt] += *(const f32x4*)(pb + (j * 4 + nt) * 1024);
    }
    __syncthreads();
    // T3: wg1 -> scrA (j4-7), wg3 -> scrB (j4-7)
    if (wg == 1 || wg == 3) {
        char* pb = (wg == 1 ? scrA : scrB) + lane * 16;
#pragma unroll
        for (int j = 4; j < 8; ++j)
#pragma unroll
            for (int nt = 0; nt < 4; ++nt)
                *(f32x4*)(pb + ((j - 4) * 4 + nt) * 1024) = acc[j][nt];
    }
    __syncthreads();
    // T4: wg0 += scrA, wg2 += scrB (j4-7); T5: wg0 -> scrA (j4-7), wg2 -> scrB (j0-3)
    if (wg == 0 || wg == 2) {
        const char* pb = (wg == 0 ? scrA : scrB) + lane * 16;
#pragma unroll
        for (int j = 4; j < 8; ++j)
#pragma unroll
            for (int nt = 0; nt < 4; ++nt)
                acc[j][nt] += *(const f32x4*)(pb + ((j - 4) * 4 + nt) * 1024);
        if (wg == 0) {
#pragma unroll
            for (int j = 4; j < 8; ++j)
#pragma unroll
                for (int nt = 0; nt < 4; ++nt)
                    *(f32x4*)(scrA + ((j - 4) * 4 + nt) * 1024 + lane * 16) = acc[j][nt];
        } else {
#pragma unroll
            for (int j = 0; j < 4; ++j)
#pragma unroll
                for (int nt = 0; nt < 4; ++nt)
                    *(f32x4*)(scrB + (j * 4 + nt) * 1024 + lane * 16) = acc[j][nt];
        }
    }
    __syncthreads();
    // T6: wg0 -> X rows 0..63; wg2 -> X rows 64..127 (X at ush sl*8192)
    const int xb = sl * 8192;
    if (wg == 0) {
#pragma unroll
        for (int j = 0; j < 4; ++j)
#pragma unroll
            for (int nt = 0; nt < 4; ++nt) {
                acc[j][nt] += *(const f32x4*)(scrB + (j * 4 + nt) * 1024 + lane * 16);
#pragma unroll
                for (int rv = 0; rv < 4; ++rv) {
                    const int row = j * 16 + 4 * g + rv;
                    const int col = nt * 16 + m;
                    lds[xb + row * 64 + (((col >> 3) ^ (row & 7)) << 3) + (col & 7)] = f2bf(acc[j][nt][rv]);
                }
            }
    } else if (wg == 2) {
#pragma unroll
        for (int j = 4; j < 8; ++j)
#pragma unroll
            for (int nt = 0; nt < 4; ++nt) {
                acc[j][nt] += *(const f32x4*)(scrA + ((j - 4) * 4 + nt) * 1024 + lane * 16);
#pragma unroll
                for (int rv = 0; rv < 4; ++rv) {
                    const int row = j * 16 + 4 * g + rv;
                    const int col = nt * 16 + m;
                    lds[xb + row * 64 + (((col >> 3) ^ (row & 7)) << 3) + (col & 7)] = f2bf(acc[j][nt][rv]);
                }
            }
    }
    __syncthreads();  // X complete; scratch dead; acc dead everywhere

    // ---- residual prefetch HERE (acc dead; MLP peak ~170+32 regs, fits) ----
    float xr[2][4][4];
#pragma unroll
    for (int mt = 0; mt < 2; ++mt)
#pragma unroll
        for (int nt = 0; nt < 4; ++nt)
#pragma unroll
            for (int rv = 0; rv < 4; ++rv)
                xr[mt][nt][rv] = xin[base + (size_t)((wg + 4 * mt) * 16 + 4 * g + rv) * tmul + nt * 16 + m];

    // ---- Phase 3/4: MLP in two 128-col hidden halves; H(sl) at ush 18432+sl*16384 ----
    const int hb = 18432 + sl * 16384;  // ush offset, row stride 128 ush
    float b2v[4];
#pragma unroll
    for (int nt = 0; nt < 4; ++nt) b2v[nt] = b2[nt * 16 + m];
    f32x4 acc2[2][4];
#pragma unroll
    for (int mt = 0; mt < 2; ++mt)
#pragma unroll
        for (int nt = 0; nt < 4; ++nt) {
            f32x4 z = {b2v[nt], b2v[nt], b2v[nt], b2v[nt]};
            acc2[mt][nt] = z;
        }

#pragma unroll
    for (int half = 0; half < 2; ++half) {
        f32x4 acc1[8][2];
#pragma unroll
        for (int mt = 0; mt < 8; ++mt)
#pragma unroll
            for (int nt = 0; nt < 2; ++nt) {
                const float bv = half ? b1vb[nt] : b1va[nt];
                f32x4 z = {bv, bv, bv, bv};
                acc1[mt][nt] = z;
            }
#pragma unroll
        for (int mt = 0; mt < 8; ++mt) {
            const int row = mt * 16 + m;
            const int c0 = (g ^ (row & 7)) << 3;
            bf16x8 a0 = *(const bf16x8*)&lds[xb + row * 64 + c0];
            bf16x8 a1 = *(const bf16x8*)&lds[xb + row * 64 + (c0 ^ 32)];
#pragma unroll
            for (int nt = 0; nt < 2; ++nt) {
                const bf16x8 w0f = half ? bw1b[nt][0] : bw1a[nt][0];
                const bf16x8 w1f = half ? bw1b[nt][1] : bw1a[nt][1];
                acc1[mt][nt] = __builtin_amdgcn_mfma_f32_16x16x32_bf16(a0, w0f, acc1[mt][nt], 0, 0, 0);
                acc1[mt][nt] = __builtin_amdgcn_mfma_f32_16x16x32_bf16(a1, w1f, acc1[mt][nt], 0, 0, 0);
            }
        }
#pragma unroll
        for (int mt = 0; mt < 8; ++mt)
#pragma unroll
            for (int nt = 0; nt < 2; ++nt) {
                const int col = wg * 32 + nt * 16 + m;
                const int c = col >> 3, jj = col & 7;
#pragma unroll
                for (int rv = 0; rv < 4; ++rv) {
                    const int row = mt * 16 + 4 * g + rv;
                    lds[hb + row * 128 + ((c ^ (row & 7)) << 3) + jj] = f2bf(gelu_fast(acc1[mt][nt][rv]));
                }
            }
        __syncthreads();  // H halves complete (both seqs)

        // GEMM2 partial: K chunk [128*half, 128*half+128)
#pragma unroll
        for (int j = 0; j < 4; ++j) {
            bf16x8 aa[2];
#pragma unroll
            for (int mt = 0; mt < 2; ++mt) {
                const int row = (wg + 4 * mt) * 16 + m;
                aa[mt] = *(const bf16x8*)&lds[hb + row * 128 + (((4 * j + g) ^ (row & 7)) << 3)];
            }
#pragma unroll
            for (int nt = 0; nt < 4; ++nt) {
                const int row = nt * 16 + m;
                bf16x8 bfr = *(const bf16x8*)&w2t[row * 256 + half * 128 + (4 * j + g) * 8];
                acc2[0][nt] = __builtin_amdgcn_mfma_f32_16x16x32_bf16(aa[0], bfr, acc2[0][nt], 0, 0, 0);
                acc2[1][nt] = __builtin_amdgcn_mfma_f32_16x16x32_bf16(aa[1], bfr, acc2[1][nt], 0, 0, 0);
            }
        }
        if (half == 0) __syncthreads();  // H region reused by half 1
    }

    // ---- store with prefetched residual ----
#pragma unroll
    for (int mt = 0; mt < 2; ++mt)
#pragma unroll
        for (int nt = 0; nt < 4; ++nt)
#pragma unroll
            for (int rv = 0; rv < 4; ++rv) {
                const int row = (wg + 4 * mt) * 16 + 4 * g + rv;
                const int col = nt * 16 + m;
                const size_t xi = base + (size_t)row * tmul + col;
                xout[xi] = xr[mt][nt][rv] + acc2[mt][nt][rv];
            }
}

extern "C" void kernel_launch(void* const* d_in, const int* in_sizes, int n_in,
                              void* d_out, int out_size, void* d_ws, size_t ws_size,
                              hipStream_t stream) {
    const float* v         = (const float*)d_in[0];
    const float* gamma_row = (const float*)d_in[1];
    const float* beta_row  = (const float*)d_in[2];
    const float* gamma_col = (const float*)d_in[3];
    const float* beta_col  = (const float*)d_in[4];
    const float* mp_row    = (const float*)d_in[5];
    const float* mm_row    = (const float*)d_in[6];
    const float* mp_col    = (const float*)d_in[7];
    const float* mm_col    = (const float*)d_in[8];
    const float* w1_row    = (const float*)d_in[9];
    const float* b1_row    = (const float*)d_in[10];
    const float* w2_row    = (const float*)d_in[11];
    const float* b2_row    = (const float*)d_in[12];
    const float* w1_col    = (const float*)d_in[13];
    const float* b1_col    = (const float*)d_in[14];
    const float* w2_col    = (const float*)d_in[15];
    const float* b2_col    = (const float*)d_in[16];
    const float* phi_row   = (const float*)d_in[17];
    const float* phi_col   = (const float*)d_in[18];
    float* out = (float*)d_out;
    char* ws   = (char*)d_ws;

    unsigned short* GfR  = (unsigned short*)ws;                      // 1 MB
    unsigned short* GfC  = (unsigned short*)(ws + (1u << 20));       // 1 MB
    unsigned short* w1tR = (unsigned short*)(ws + (2u << 20));
    unsigned short* w2tR = (unsigned short*)(ws + (2u << 20) + 32768);
    unsigned short* w1tC = (unsigned short*)(ws + (2u << 20) + 65536);
    unsigned short* w2tC = (unsigned short*)(ws + (2u << 20) + 98304);

    init_kernel<<<260, 256, 0, stream>>>(phi_row, mp_row, mm_row, GfR,
                                         phi_col, mp_col, mm_col, GfC,
                                         w1_row, w1_col, w2_row, w2_col,
                                         w1tR, w1tC, w2tR, w2tC);

    // row pass: seq=(b,h), rmul=8192 (h stride), tmul=64 (w stride)
    fused_kernel<<<256, 512, 0, stream>>>(v, out, GfR, w1tR, w2tR, b1_row, b2_row,
                                          gamma_row, beta_row, 8192, 64);
    // col pass: seq=(b,w), rmul=64 (w stride), tmul=8192 (h stride)
    fused_kernel<<<256, 512, 0, stream>>>(out, out, GfC, w1tC, w2tC, b1_col, b2_col,
                                          gamma_col, beta_col, 64, 8192);
}

// Round 17
// 126.577 us; speedup vs baseline: 1.2188x; 1.1352x over previous
//
#include <hip/hip_runtime.h>

typedef __attribute__((ext_vector_type(8))) short bf16x8;
typedef __attribute__((ext_vector_type(4))) float f32x4;

__device__ __forceinline__ float gelu_fast(float x) {
    const float u = 0.7978845608028654f * x * (1.0f + 0.044715f * x * x);
    return x * __builtin_amdgcn_rcpf(1.0f + __expf(-2.0f * u));
}

__device__ __forceinline__ unsigned short f2bf(float x) {
    union { float f; unsigned int u; } v; v.f = x;
    unsigned int r = v.u + 0x7FFF + ((v.u >> 16) & 1);
    return (unsigned short)(r >> 16);
}

// blocks [0,256): Gf production (fragment-major). blocks [256,260): weight transposes.
__global__ __launch_bounds__(256) void init_kernel(const float* __restrict__ phi_r, const float* __restrict__ mp_r,
                                                   const float* __restrict__ mm_r, unsigned short* __restrict__ GcR,
                                                   const float* __restrict__ phi_c, const float* __restrict__ mp_c,
                                                   const float* __restrict__ mm_c, unsigned short* __restrict__ GcC,
                                                   const float* __restrict__ w1r, const float* __restrict__ w1c,
                                                   const float* __restrict__ w2r, const float* __restrict__ w2c,
                                                   unsigned short* __restrict__ w1tr, unsigned short* __restrict__ w1tc,
                                                   unsigned short* __restrict__ w2tr, unsigned short* __restrict__ w2tc) {
    const int bid = blockIdx.x, tid = threadIdx.x;
    __shared__ float phis[256];
    __shared__ unsigned short tile[4096];
    if (bid < 256) {
        const int side = bid >> 7, rem = bid & 127;
        const int chunk = rem >> 3, s0 = (rem & 7) * 16;
        const float* phi = side ? phi_c : phi_r;
        const float* mp  = side ? mp_c  : mp_r;
        const float* mm  = side ? mm_c  : mm_r;
        unsigned short* Gct = side ? GcC : GcR;
        const int i = chunk * 256 + tid;
        float pe[16], po[16];
#pragma unroll
        for (int k = 0; k < 16; ++k) {
            const float a = mp[k * 4096 + i];
            const float b = mm[k * 4096 + i];
            pe[k] = a + b; po[k] = a - b;
        }
        phis[tid] = phi[s0 * 16 + tid];
        __syncthreads();
        const int e = tid & 63, dl = tid >> 6;
        const int d0 = chunk * 4;
        const int kk = d0 >> 5, g3 = (d0 >> 3) & 3, jl0 = d0 & 7;
#pragma unroll
        for (int sb = 0; sb < 16; ++sb) {
            const int s = s0 + sb;
            const float* pk = &phis[sb * 16];
            float acc = 0.0f;
            if (s & 1) {
#pragma unroll
                for (int k = 0; k < 16; ++k) acc += pk[k] * po[k];
            } else {
#pragma unroll
                for (int k = 0; k < 16; ++k) acc += pk[k] * pe[k];
            }
            tile[sb * 256 + e * 4 + dl] = f2bf(acc);
        }
        __syncthreads();
#pragma unroll
        for (int it = 0; it < 4; ++it) {
            const int p = it * 256 + tid;
            const int sb = p >> 6, ee = p & 63;
            uint2 v = *(const uint2*)&tile[sb * 256 + ee * 4];
            *(uint2*)&Gct[(size_t)(s0 + sb) * 4096 + (((ee >> 4) << 1) + kk) * 512 +
                          (g3 * 16 + (ee & 15)) * 8 + jl0] = v;
        }
    } else {
        const int b = bid - 256;
        if (b < 2) {
            const float* w1 = b ? w1c : w1r;
            unsigned short* dst = b ? w1tc : w1tr;
            const int n = tid;
            for (int k = 0; k < 64; ++k) dst[n * 64 + k] = f2bf(w1[k * 256 + n]);
        } else {
            const float* w2 = (b == 3) ? w2c : w2r;
            unsigned short* dst = (b == 3) ? w2tc : w2tr;
            const int n = tid & 63, kq = tid >> 6;
            for (int kk2 = 0; kk2 < 64; ++kk2) {
                const int k = kq * 64 + kk2;
                dst[n * 256 + k] = f2bf(w2[k * 64 + n]);
            }
        }
    }
}

// Fused pass (R14 champion + T5 setprio around MFMA clusters).
// 1 seq/block, 4 waves, grid 512 (2 blocks/CU). 50 KB LDS.
// REGISTER LEDGER (unified file, 2 waves/SIMD => 256/wave):
//   spec phase:  acc[8][4](128) + Ba/Bb(64) + misc(~60) = ~252  <- SATURATED, add NOTHING
//   reduction:   acc live through T6                             <- add NOTHING (R13 spill)
//   MLP phase:   ~170+xr(32) = ~200                              <- xr fits here only
// __launch_bounds__ min-waves stays 2 (R10: (256,3) caps regs ~85 -> acc spills).
// setprio(1) wraps MFMA clusters: free-running waves (no spec barriers) at different
// phases -> MFMA-entering wave wins issue arbitration over load-issuing twin (m191 regime).
// LDS bytes (time-shared):
//   ys [0,18432) | scrA [18432,34816) scrB [34816,51200) | X [0,16384) | H [16384,49152)
#define SPEC_BODY(RR, BC, BN)                                                        \
    {                                                                                \
        const int s_ = 4 * (RR) + w;                                                 \
        if ((RR) < 31) {                                                             \
            const unsigned short* gq = Gf + (size_t)(s_ + 4) * 4096 + lane * 8;      \
            _Pragma("unroll")                                                        \
            for (int f = 0; f < 8; ++f) BN[f] = *(const bf16x8*)(gq + f * 512);      \
        }                                                                            \
        const int jmin_ = __builtin_amdgcn_readfirstlane(s_ >> 4);                   \
        __builtin_amdgcn_s_setprio(1);                                               \
        _Pragma("unroll")                                                            \
        for (int j = 0; j < 8; ++j) {                                                \
            if (j >= jmin_) {                                                        \
                const int row_ = 16 + 16 * j - s_ + m;                               \
                const int c0_ = (g ^ (row_ & 7)) << 3;                               \
                const int ab_ = row_ * 64;                                           \
                bf16x8 a0_ = *(const bf16x8*)&lds[ab_ + c0_];                        \
                bf16x8 a1_ = *(const bf16x8*)&lds[ab_ + (c0_ ^ 32)];                 \
                _Pragma("unroll")                                                    \
                for (int nt = 0; nt < 4; ++nt) {                                     \
                    acc[j][nt] = __builtin_amdgcn_mfma_f32_16x16x32_bf16(a0_, BC[2 * nt], acc[j][nt], 0, 0, 0);     \
                    acc[j][nt] = __builtin_amdgcn_mfma_f32_16x16x32_bf16(a1_, BC[2 * nt + 1], acc[j][nt], 0, 0, 0); \
                }                                                                    \
            }                                                                        \
        }                                                                            \
        __builtin_amdgcn_s_setprio(0);                                               \
    }

__global__ __launch_bounds__(256, 2) void fused_kernel(const float* __restrict__ xin,
                                                       float* __restrict__ xout,
                                                       const unsigned short* __restrict__ Gf,
                                                       const unsigned short* __restrict__ w1t,
                                                       const unsigned short* __restrict__ w2t,
                                                       const float* __restrict__ b1,
                                                       const float* __restrict__ b2,
                                                       const float* __restrict__ gamma,
                                                       const float* __restrict__ beta,
                                                       int rmul, int tmul) {
    __shared__ unsigned short lds[25600];  // 50 KB
    const int tid = threadIdx.x;
    const int w = tid >> 6, lane = tid & 63;
    const int seq = blockIdx.x;
    const int m = lane & 15, g = lane >> 4;
    const int bb = seq >> 7, rr = seq & 127;
    const size_t base = (size_t)bb * 1048576 + (size_t)rr * (size_t)rmul;

    // zero ys prefix rows 0..15 (bytes [0,2048))
    {
        uint2 z; z.x = 0u; z.y = 0u;
        *(uint2*)((char*)lds + tid * 8) = z;
    }

    // issue spec round-0 B load early (hides L2 latency under LN)
    bf16x8 Ba[8], Bb[8];
    {
        const unsigned short* gq = Gf + (size_t)w * 4096 + lane * 8;
#pragma unroll
        for (int f = 0; f < 8; ++f) Ba[f] = *(const bf16x8*)(gq + f * 512);
    }

    // ---- Phase 0: LayerNorm rows w*32 .. w*32+31 into swizzled ys ----
    {
        const float gl = gamma[lane], bl = beta[lane];
        float xv[32];
#pragma unroll
        for (int ti = 0; ti < 32; ++ti)
            xv[ti] = xin[base + (size_t)(w * 32 + ti) * tmul + lane];
#pragma unroll
        for (int ti = 0; ti < 32; ++ti) {
            const int t = w * 32 + ti;
            float s1 = xv[ti];
#pragma unroll
            for (int mm2 = 32; mm2 >= 1; mm2 >>= 1) s1 += __shfl_xor(s1, mm2);
            const float mu = s1 * (1.0f / 64.0f);
            const float dv = xv[ti] - mu;
            float s2 = dv * dv;
#pragma unroll
            for (int mm2 = 32; mm2 >= 1; mm2 >>= 1) s2 += __shfl_xor(s2, mm2);
            const float rstd = rsqrtf(s2 * (1.0f / 64.0f) + 1e-5f);
            const float nv = dv * rstd * gl + bl;
            lds[(t + 16) * 64 + (((lane >> 3) ^ (t & 7)) << 3) + (lane & 7)] = f2bf(nv);
        }
    }
    __syncthreads();  // ys complete

    // ---- Phase 1: spec main loop (no barriers) ----
    f32x4 acc[8][4];
#pragma unroll
    for (int j = 0; j < 8; ++j)
#pragma unroll
        for (int nt = 0; nt < 4; ++nt) {
            f32x4 z = {0.0f, 0.0f, 0.0f, 0.0f};
            acc[j][nt] = z;
        }
    for (int rp = 0; rp < 16; ++rp) {
        SPEC_BODY(2 * rp,     Ba, Bb);
        SPEC_BODY(2 * rp + 1, Bb, Ba);
    }

    // ---- Phase 2: pairwise tree reduction (32 KB scratch) ----
    char* const scrA = (char*)lds + 18432;
    char* const scrB = (char*)lds + 34816;
    // T1: w1 -> scrA (j0-3), w3 -> scrB (j0-3)
    if (w == 1 || w == 3) {
        char* pb = (w == 1 ? scrA : scrB) + lane * 16;
#pragma unroll
        for (int j = 0; j < 4; ++j)
#pragma unroll
            for (int nt = 0; nt < 4; ++nt)
                *(f32x4*)(pb + (j * 4 + nt) * 1024) = acc[j][nt];
    }
    // weight fragment loads (overlap reduction); wave owns hidden cols [32w,32w+32) per half
    bf16x8 bw1a[2][2], bw1b[2][2];
    float b1va[2], b1vb[2];
#pragma unroll
    for (int nt = 0; nt < 2; ++nt) {
        const int col0 = w * 32 + nt * 16 + m;
#pragma unroll
        for (int j = 0; j < 2; ++j) {
            bw1a[nt][j] = *(const bf16x8*)&w1t[col0 * 64 + (4 * j + g) * 8];
            bw1b[nt][j] = *(const bf16x8*)&w1t[(128 + col0) * 64 + (4 * j + g) * 8];
        }
        b1va[nt] = b1[col0];
        b1vb[nt] = b1[128 + col0];
    }
    __syncthreads();
    // T2: w0 += scrA, w2 += scrB (j0-3)
    if (w == 0 || w == 2) {
        const char* pb = (w == 0 ? scrA : scrB) + lane * 16;
#pragma unroll
        for (int j = 0; j < 4; ++j)
#pragma unroll
            for (int nt = 0; nt < 4; ++nt)
                acc[j][nt] += *(const f32x4*)(pb + (j * 4 + nt) * 1024);
    }
    __syncthreads();
    // T3: w1 -> scrA (j4-7), w3 -> scrB (j4-7)
    if (w == 1 || w == 3) {
        char* pb = (w == 1 ? scrA : scrB) + lane * 16;
#pragma unroll
        for (int j = 4; j < 8; ++j)
#pragma unroll
            for (int nt = 0; nt < 4; ++nt)
                *(f32x4*)(pb + ((j - 4) * 4 + nt) * 1024) = acc[j][nt];
    }
    __syncthreads();
    // T4: w0 += scrA, w2 += scrB (j4-7); then T5: w0 -> scrA (j4-7), w2 -> scrB (j0-3)
    if (w == 0 || w == 2) {
        const char* pb = (w == 0 ? scrA : scrB) + lane * 16;
#pragma unroll
        for (int j = 4; j < 8; ++j)
#pragma unroll
            for (int nt = 0; nt < 4; ++nt)
                acc[j][nt] += *(const f32x4*)(pb + ((j - 4) * 4 + nt) * 1024);
        if (w == 0) {
#pragma unroll
            for (int j = 4; j < 8; ++j)
#pragma unroll
                for (int nt = 0; nt < 4; ++nt)
                    *(f32x4*)(scrA + ((j - 4) * 4 + nt) * 1024 + lane * 16) = acc[j][nt];
        } else {
#pragma unroll
            for (int j = 0; j < 4; ++j)
#pragma unroll
                for (int nt = 0; nt < 4; ++nt)
                    *(f32x4*)(scrB + (j * 4 + nt) * 1024 + lane * 16) = acc[j][nt];
        }
    }
    __syncthreads();
    // T6: w0 finalizes j0-3 -> X rows 0..63; w2 finalizes j4-7 -> X rows 64..127
    if (w == 0) {
#pragma unroll
        for (int j = 0; j < 4; ++j)
#pragma unroll
            for (int nt = 0; nt < 4; ++nt) {
                acc[j][nt] += *(const f32x4*)(scrB + (j * 4 + nt) * 1024 + lane * 16);
#pragma unroll
                for (int rv = 0; rv < 4; ++rv) {
                    const int row = j * 16 + 4 * g + rv;
                    const int col = nt * 16 + m;
                    lds[row * 64 + (((col >> 3) ^ (row & 7)) << 3) + (col & 7)] = f2bf(acc[j][nt][rv]);
                }
            }
    } else if (w == 2) {
#pragma unroll
        for (int j = 4; j < 8; ++j)
#pragma unroll
            for (int nt = 0; nt < 4; ++nt) {
                acc[j][nt] += *(const f32x4*)(scrA + ((j - 4) * 4 + nt) * 1024 + lane * 16);
#pragma unroll
                for (int rv = 0; rv < 4; ++rv) {
                    const int row = j * 16 + 4 * g + rv;
                    const int col = nt * 16 + m;
                    lds[row * 64 + (((col >> 3) ^ (row & 7)) << 3) + (col & 7)] = f2bf(acc[j][nt][rv]);
                }
            }
    }
    __syncthreads();  // X complete; scratch dead; acc dead everywhere

    // ---- residual prefetch HERE (acc dead; MLP peak ~170+32 regs, fits) ----
    float xr[2][4][4];
#pragma unroll
    for (int mt = 0; mt < 2; ++mt)
#pragma unroll
        for (int nt = 0; nt < 4; ++nt)
#pragma unroll
            for (int rv = 0; rv < 4; ++rv)
                xr[mt][nt][rv] = xin[base + (size_t)((w + 4 * mt) * 16 + 4 * g + rv) * tmul + nt * 16 + m];

    // ---- Phase 3/4: MLP in two 128-col hidden halves; H at ush offset 8192, row stride 128 ush ----
    float b2v[4];
#pragma unroll
    for (int nt = 0; nt < 4; ++nt) b2v[nt] = b2[nt * 16 + m];
    f32x4 acc2[2][4];
#pragma unroll
    for (int mt = 0; mt < 2; ++mt)
#pragma unroll
        for (int nt = 0; nt < 4; ++nt) {
            f32x4 z = {b2v[nt], b2v[nt], b2v[nt], b2v[nt]};
            acc2[mt][nt] = z;
        }

#pragma unroll
    for (int half = 0; half < 2; ++half) {
        // GEMM1 half: H[:, 128*half + 32w .. +32) = gelu(X @ W1half + b1half)
        f32x4 acc1[8][2];
#pragma unroll
        for (int mt = 0; mt < 8; ++mt)
#pragma unroll
            for (int nt = 0; nt < 2; ++nt) {
                const float bv = half ? b1vb[nt] : b1va[nt];
                f32x4 z = {bv, bv, bv, bv};
                acc1[mt][nt] = z;
            }
        __builtin_amdgcn_s_setprio(1);
#pragma unroll
        for (int mt = 0; mt < 8; ++mt) {
            const int row = mt * 16 + m;
            const int c0 = (g ^ (row & 7)) << 3;
            bf16x8 a0 = *(const bf16x8*)&lds[row * 64 + c0];
            bf16x8 a1 = *(const bf16x8*)&lds[row * 64 + (c0 ^ 32)];
#pragma unroll
            for (int nt = 0; nt < 2; ++nt) {
                const bf16x8 w0f = half ? bw1b[nt][0] : bw1a[nt][0];
                const bf16x8 w1f = half ? bw1b[nt][1] : bw1a[nt][1];
                acc1[mt][nt] = __builtin_amdgcn_mfma_f32_16x16x32_bf16(a0, w0f, acc1[mt][nt], 0, 0, 0);
                acc1[mt][nt] = __builtin_amdgcn_mfma_f32_16x16x32_bf16(a1, w1f, acc1[mt][nt], 0, 0, 0);
            }
        }
        __builtin_amdgcn_s_setprio(0);
        // gelu + H half to LDS (cols within half: 32w + nt*16 + m)
#pragma unroll
        for (int mt = 0; mt < 8; ++mt)
#pragma unroll
            for (int nt = 0; nt < 2; ++nt) {
                const int col = w * 32 + nt * 16 + m;
                const int c = col >> 3, jj = col & 7;
#pragma unroll
                for (int rv = 0; rv < 4; ++rv) {
                    const int row = mt * 16 + 4 * g + rv;
                    lds[8192 + row * 128 + ((c ^ (row & 7)) << 3) + jj] = f2bf(gelu_fast(acc1[mt][nt][rv]));
                }
            }
        __syncthreads();  // H half complete

        // GEMM2 partial: K chunk [128*half, 128*half+128)
        __builtin_amdgcn_s_setprio(1);
#pragma unroll
        for (int j = 0; j < 4; ++j) {
            bf16x8 aa[2];
#pragma unroll
            for (int mt = 0; mt < 2; ++mt) {
                const int row = (w + 4 * mt) * 16 + m;
                aa[mt] = *(const bf16x8*)&lds[8192 + row * 128 + (((4 * j + g) ^ (row & 7)) << 3)];
            }
#pragma unroll
            for (int nt = 0; nt < 4; ++nt) {
                const int row = nt * 16 + m;
                bf16x8 bfr = *(const bf16x8*)&w2t[row * 256 + half * 128 + (4 * j + g) * 8];
                acc2[0][nt] = __builtin_amdgcn_mfma_f32_16x16x32_bf16(aa[0], bfr, acc2[0][nt], 0, 0, 0);
                acc2[1][nt] = __builtin_amdgcn_mfma_f32_16x16x32_bf16(aa[1], bfr, acc2[1][nt], 0, 0, 0);
            }
        }
        __builtin_amdgcn_s_setprio(0);
        if (half == 0) __syncthreads();  // H region reused by half 1
    }

    // ---- store with prefetched residual ----
#pragma unroll
    for (int mt = 0; mt < 2; ++mt)
#pragma unroll
        for (int nt = 0; nt < 4; ++nt)
#pragma unroll
            for (int rv = 0; rv < 4; ++rv) {
                const int row = (w + 4 * mt) * 16 + 4 * g + rv;
                const int col = nt * 16 + m;
                const size_t xi = base + (size_t)row * tmul + col;
                xout[xi] = xr[mt][nt][rv] + acc2[mt][nt][rv];
            }
}

extern "C" void kernel_launch(void* const* d_in, const int* in_sizes, int n_in,
                              void* d_out, int out_size, void* d_ws, size_t ws_size,
                              hipStream_t stream) {
    const float* v         = (const float*)d_in[0];
    const float* gamma_row = (const float*)d_in[1];
    const float* beta_row  = (const float*)d_in[2];
    const float* gamma_col = (const float*)d_in[3];
    const float* beta_col  = (const float*)d_in[4];
    const float* mp_row    = (const float*)d_in[5];
    const float* mm_row    = (const float*)d_in[6];
    const float* mp_col    = (const float*)d_in[7];
    const float* mm_col    = (const float*)d_in[8];
    const float* w1_row    = (const float*)d_in[9];
    const float* b1_row    = (const float*)d_in[10];
    const float* w2_row    = (const float*)d_in[11];
    const float* b2_row    = (const float*)d_in[12];
    const float* w1_col    = (const float*)d_in[13];
    const float* b1_col    = (const float*)d_in[14];
    const float* w2_col    = (const float*)d_in[15];
    const float* b2_col    = (const float*)d_in[16];
    const float* phi_row   = (const float*)d_in[17];
    const float* phi_col   = (const float*)d_in[18];
    float* out = (float*)d_out;
    char* ws   = (char*)d_ws;

    unsigned short* GfR  = (unsigned short*)ws;                      // 1 MB
    unsigned short* GfC  = (unsigned short*)(ws + (1u << 20));       // 1 MB
    unsigned short* w1tR = (unsigned short*)(ws + (2u << 20));
    unsigned short* w2tR = (unsigned short*)(ws + (2u << 20) + 32768);
    unsigned short* w1tC = (unsigned short*)(ws + (2u << 20) + 65536);
    unsigned short* w2tC = (unsigned short*)(ws + (2u << 20) + 98304);

    init_kernel<<<260, 256, 0, stream>>>(phi_row, mp_row, mm_row, GfR,
                                         phi_col, mp_col, mm_col, GfC,
                                         w1_row, w1_col, w2_row, w2_col,
                                         w1tR, w1tC, w2tR, w2tC);

    // row pass: seq=(b,h), rmul=8192 (h stride), tmul=64 (w stride)
    fused_kernel<<<512, 256, 0, stream>>>(v, out, GfR, w1tR, w2tR, b1_row, b2_row,
                                          gamma_row, beta_row, 8192, 64);
    // col pass: seq=(b,w), rmul=64 (w stride), tmul=8192 (h stride)
    fused_kernel<<<512, 256, 0, stream>>>(out, out, GfC, w1tC, w2tC, b1_col, b2_col,
                                          gamma_col, beta_col, 64, 8192);
}

// Round 18
// 116.039 us; speedup vs baseline: 1.3295x; 1.0908x over previous
//
#include <hip/hip_runtime.h>
#include <hip/hip_fp8.h>

typedef __attribute__((ext_vector_type(8))) short bf16x8;
typedef __attribute__((ext_vector_type(4))) float f32x4;

__device__ __forceinline__ float gelu_fast(float x) {
    const float u = 0.7978845608028654f * x * (1.0f + 0.044715f * x * x);
    return x * __builtin_amdgcn_rcpf(1.0f + __expf(-2.0f * u));
}

__device__ __forceinline__ unsigned short f2bf(float x) {
    union { float f; unsigned int u; } v; v.f = x;
    unsigned int r = v.u + 0x7FFF + ((v.u >> 16) & 1);
    return (unsigned short)(r >> 16);
}

__device__ __forceinline__ unsigned char f2fp8(float x) {
    __hip_fp8_e4m3 h(x);  // OCP e4m3fn, saturating
    return *(unsigned char*)&h;
}

// blocks [0,256): Gf8 production (fp8 e4m3, scaled x32, fragment-major:
//   Gf8[s][frag=nt*2+kk][lane=g*16+m][8B] = fp8(32*Gc[s][e=nt*16+m][d=kk*32+g*8+j]))
// blocks [256,260): weight transposes (bf16, unchanged).
__global__ __launch_bounds__(256) void init_kernel(const float* __restrict__ phi_r, const float* __restrict__ mp_r,
                                                   const float* __restrict__ mm_r, unsigned char* __restrict__ GfR,
                                                   const float* __restrict__ phi_c, const float* __restrict__ mp_c,
                                                   const float* __restrict__ mm_c, unsigned char* __restrict__ GfC,
                                                   const float* __restrict__ w1r, const float* __restrict__ w1c,
                                                   const float* __restrict__ w2r, const float* __restrict__ w2c,
                                                   unsigned short* __restrict__ w1tr, unsigned short* __restrict__ w1tc,
                                                   unsigned short* __restrict__ w2tr, unsigned short* __restrict__ w2tc) {
    const int bid = blockIdx.x, tid = threadIdx.x;
    __shared__ float phis[256];
    __shared__ unsigned char tile8[4096];  // 16 s x 256 fp8 (e-major, d-minor)
    if (bid < 256) {
        const int side = bid >> 7, rem = bid & 127;
        const int chunk = rem >> 3, s0 = (rem & 7) * 16;
        const float* phi = side ? phi_c : phi_r;
        const float* mp  = side ? mp_c  : mp_r;
        const float* mm  = side ? mm_c  : mm_r;
        unsigned char* Gf8 = side ? GfC : GfR;
        const int i = chunk * 256 + tid;
        float pe[16], po[16];
#pragma unroll
        for (int k = 0; k < 16; ++k) {
            const float a = mp[k * 4096 + i];
            const float b = mm[k * 4096 + i];
            pe[k] = a + b; po[k] = a - b;
        }
        phis[tid] = phi[s0 * 16 + tid];
        __syncthreads();
        const int e = tid & 63, dl = tid >> 6;
        const int d0 = chunk * 4;
        const int kk = d0 >> 5, g3 = (d0 >> 3) & 3, jl0 = d0 & 7;
#pragma unroll
        for (int sb = 0; sb < 16; ++sb) {
            const int s = s0 + sb;
            const float* pk = &phis[sb * 16];
            float acc = 0.0f;
            if (s & 1) {
#pragma unroll
                for (int k = 0; k < 16; ++k) acc += pk[k] * po[k];
            } else {
#pragma unroll
                for (int k = 0; k < 16; ++k) acc += pk[k] * pe[k];
            }
            tile8[sb * 256 + e * 4 + dl] = f2fp8(acc * 32.0f);
        }
        __syncthreads();
#pragma unroll
        for (int it = 0; it < 4; ++it) {
            const int p = it * 256 + tid;
            const int sb = p >> 6, ee = p & 63;
            unsigned int v = *(const unsigned int*)&tile8[sb * 256 + ee * 4];
            *(unsigned int*)&Gf8[(size_t)(s0 + sb) * 4096 + (((ee >> 4) << 1) + kk) * 512 +
                                 (g3 * 16 + (ee & 15)) * 8 + jl0] = v;
        }
    } else {
        const int b = bid - 256;
        if (b < 2) {
            const float* w1 = b ? w1c : w1r;
            unsigned short* dst = b ? w1tc : w1tr;
            const int n = tid;
            for (int k = 0; k < 64; ++k) dst[n * 64 + k] = f2bf(w1[k * 256 + n]);
        } else {
            const float* w2 = (b == 3) ? w2c : w2r;
            unsigned short* dst = (b == 3) ? w2tc : w2tr;
            const int n = tid & 63, kq = tid >> 6;
            for (int kk2 = 0; kk2 < 64; ++kk2) {
                const int k = kq * 64 + kk2;
                dst[n * 256 + k] = f2bf(w2[k * 64 + n]);
            }
        }
    }
}

// Fused pass (R17 champion with fp8 spec operands).
// 1 seq/block, 4 waves, grid 512 (2 blocks/CU). 50 KB LDS.
// spec: y and Gc in fp8 e4m3 (Gc scaled x32; acc unscaled by 1/32 at X write).
// B-stream and ys HALVE vs bf16: Gf8 = 512 KB, B-frag = 8 B/lane, A = ds_read_b64.
// REGISTER LEDGER (2 waves/SIMD => 256/wave): spec peak = acc(128) + Ba/Bb(32) +
// misc(~60) = ~220. min-waves stays 2 (R10: (256,3) caps regs ~85 -> spills).
// xr residual prefetch only post-T6 (R13: earlier spills).
// LDS bytes (time-shared):
//   ys(fp8) [0,9216) | scrA [18432,34816) scrB [34816,51200) | X(bf16) [0,16384) | H [16384,49152)
#define SPEC_BODY(RR, BC, BN)                                                        \
    {                                                                                \
        const int s_ = 4 * (RR) + w;                                                 \
        if ((RR) < 31) {                                                             \
            const unsigned char* gq = Gf8 + (size_t)(s_ + 4) * 4096 + lane * 8;      \
            _Pragma("unroll")                                                        \
            for (int f = 0; f < 8; ++f) BN[f] = *(const long*)(gq + f * 512);        \
        }                                                                            \
        const int jmin_ = __builtin_amdgcn_readfirstlane(s_ >> 4);                   \
        __builtin_amdgcn_s_setprio(1);                                               \
        _Pragma("unroll")                                                            \
        for (int j = 0; j < 8; ++j) {                                                \
            if (j >= jmin_) {                                                        \
                const int row_ = 16 + 16 * j - s_ + m;                               \
                const int c0_ = (g ^ (row_ & 7)) << 3;                               \
                const int ab_ = row_ * 64;                                           \
                long a0_ = *(const long*)&lds8[ab_ + c0_];                           \
                long a1_ = *(const long*)&lds8[ab_ + (c0_ ^ 32)];                    \
                _Pragma("unroll")                                                    \
                for (int nt = 0; nt < 4; ++nt) {                                     \
                    acc[j][nt] = __builtin_amdgcn_mfma_f32_16x16x32_fp8_fp8(a0_, BC[2 * nt], acc[j][nt], 0, 0, 0);     \
                    acc[j][nt] = __builtin_amdgcn_mfma_f32_16x16x32_fp8_fp8(a1_, BC[2 * nt + 1], acc[j][nt], 0, 0, 0); \
                }                                                                    \
            }                                                                        \
        }                                                                            \
        __builtin_amdgcn_s_setprio(0);                                               \
    }

__global__ __launch_bounds__(256, 2) void fused_kernel(const float* __restrict__ xin,
                                                       float* __restrict__ xout,
                                                       const unsigned char* __restrict__ Gf8,
                                                       const unsigned short* __restrict__ w1t,
                                                       const unsigned short* __restrict__ w2t,
                                                       const float* __restrict__ b1,
                                                       const float* __restrict__ b2,
                                                       const float* __restrict__ gamma,
                                                       const float* __restrict__ beta,
                                                       int rmul, int tmul) {
    __shared__ unsigned char lds8[51200];  // 50 KB (byte view)
    unsigned short* const ldsu = (unsigned short*)lds8;  // bf16 view for X/H
    const int tid = threadIdx.x;
    const int w = tid >> 6, lane = tid & 63;
    const int seq = blockIdx.x;
    const int m = lane & 15, g = lane >> 4;
    const int bb = seq >> 7, rr = seq & 127;
    const size_t base = (size_t)bb * 1048576 + (size_t)rr * (size_t)rmul;

    // zero ys prefix rows 0..15 (bytes [0,1024))
    *(unsigned int*)&lds8[tid * 4] = 0u;

    // issue spec round-0 B load early (hides L2 latency under LN)
    long Ba[8], Bb[8];
    {
        const unsigned char* gq = Gf8 + (size_t)w * 4096 + lane * 8;
#pragma unroll
        for (int f = 0; f < 8; ++f) Ba[f] = *(const long*)(gq + f * 512);
    }

    // ---- Phase 0: LayerNorm rows w*32 .. w*32+31 into swizzled fp8 ys ----
    {
        const float gl = gamma[lane], bl = beta[lane];
        float xv[32];
#pragma unroll
        for (int ti = 0; ti < 32; ++ti)
            xv[ti] = xin[base + (size_t)(w * 32 + ti) * tmul + lane];
#pragma unroll
        for (int ti = 0; ti < 32; ++ti) {
            const int t = w * 32 + ti;
            float s1 = xv[ti];
#pragma unroll
            for (int mm2 = 32; mm2 >= 1; mm2 >>= 1) s1 += __shfl_xor(s1, mm2);
            const float mu = s1 * (1.0f / 64.0f);
            const float dv = xv[ti] - mu;
            float s2 = dv * dv;
#pragma unroll
            for (int mm2 = 32; mm2 >= 1; mm2 >>= 1) s2 += __shfl_xor(s2, mm2);
            const float rstd = rsqrtf(s2 * (1.0f / 64.0f) + 1e-5f);
            const float nv = dv * rstd * gl + bl;
            lds8[(t + 16) * 64 + (((lane >> 3) ^ (t & 7)) << 3) + (lane & 7)] = f2fp8(nv);
        }
    }
    __syncthreads();  // ys complete

    // ---- Phase 1: spec main loop (no barriers) ----
    f32x4 acc[8][4];
#pragma unroll
    for (int j = 0; j < 8; ++j)
#pragma unroll
        for (int nt = 0; nt < 4; ++nt) {
            f32x4 z = {0.0f, 0.0f, 0.0f, 0.0f};
            acc[j][nt] = z;
        }
    for (int rp = 0; rp < 16; ++rp) {
        SPEC_BODY(2 * rp,     Ba, Bb);
        SPEC_BODY(2 * rp + 1, Bb, Ba);
    }

    // ---- Phase 2: pairwise tree reduction (32 KB scratch) ----
    char* const scrA = (char*)lds8 + 18432;
    char* const scrB = (char*)lds8 + 34816;
    if (w == 1 || w == 3) {
        char* pb = (w == 1 ? scrA : scrB) + lane * 16;
#pragma unroll
        for (int j = 0; j < 4; ++j)
#pragma unroll
            for (int nt = 0; nt < 4; ++nt)
                *(f32x4*)(pb + (j * 4 + nt) * 1024) = acc[j][nt];
    }
    // weight fragment loads (overlap reduction); wave owns hidden cols [32w,32w+32) per half
    bf16x8 bw1a[2][2], bw1b[2][2];
    float b1va[2], b1vb[2];
#pragma unroll
    for (int nt = 0; nt < 2; ++nt) {
        const int col0 = w * 32 + nt * 16 + m;
#pragma unroll
        for (int j = 0; j < 2; ++j) {
            bw1a[nt][j] = *(const bf16x8*)&w1t[col0 * 64 + (4 * j + g) * 8];
            bw1b[nt][j] = *(const bf16x8*)&w1t[(128 + col0) * 64 + (4 * j + g) * 8];
        }
        b1va[nt] = b1[col0];
        b1vb[nt] = b1[128 + col0];
    }
    __syncthreads();
    if (w == 0 || w == 2) {
        const char* pb = (w == 0 ? scrA : scrB) + lane * 16;
#pragma unroll
        for (int j = 0; j < 4; ++j)
#pragma unroll
            for (int nt = 0; nt < 4; ++nt)
                acc[j][nt] += *(const f32x4*)(pb + (j * 4 + nt) * 1024);
    }
    __syncthreads();
    if (w == 1 || w == 3) {
        char* pb = (w == 1 ? scrA : scrB) + lane * 16;
#pragma unroll
        for (int j = 4; j < 8; ++j)
#pragma unroll
            for (int nt = 0; nt < 4; ++nt)
                *(f32x4*)(pb + ((j - 4) * 4 + nt) * 1024) = acc[j][nt];
    }
    __syncthreads();
    if (w == 0 || w == 2) {
        const char* pb = (w == 0 ? scrA : scrB) + lane * 16;
#pragma unroll
        for (int j = 4; j < 8; ++j)
#pragma unroll
            for (int nt = 0; nt < 4; ++nt)
                acc[j][nt] += *(const f32x4*)(pb + ((j - 4) * 4 + nt) * 1024);
        if (w == 0) {
#pragma unroll
            for (int j = 4; j < 8; ++j)
#pragma unroll
                for (int nt = 0; nt < 4; ++nt)
                    *(f32x4*)(scrA + ((j - 4) * 4 + nt) * 1024 + lane * 16) = acc[j][nt];
        } else {
#pragma unroll
            for (int j = 0; j < 4; ++j)
#pragma unroll
                for (int nt = 0; nt < 4; ++nt)
                    *(f32x4*)(scrB + (j * 4 + nt) * 1024 + lane * 16) = acc[j][nt];
        }
    }
    __syncthreads();
    // T6: finalize -> X bf16 (acc carries 32x scale; undo here)
    if (w == 0) {
#pragma unroll
        for (int j = 0; j < 4; ++j)
#pragma unroll
            for (int nt = 0; nt < 4; ++nt) {
                acc[j][nt] += *(const f32x4*)(scrB + (j * 4 + nt) * 1024 + lane * 16);
#pragma unroll
                for (int rv = 0; rv < 4; ++rv) {
                    const int row = j * 16 + 4 * g + rv;
                    const int col = nt * 16 + m;
                    ldsu[row * 64 + (((col >> 3) ^ (row & 7)) << 3) + (col & 7)] = f2bf(acc[j][nt][rv] * 0.03125f);
                }
            }
    } else if (w == 2) {
#pragma unroll
        for (int j = 4; j < 8; ++j)
#pragma unroll
            for (int nt = 0; nt < 4; ++nt) {
                acc[j][nt] += *(const f32x4*)(scrA + ((j - 4) * 4 + nt) * 1024 + lane * 16);
#pragma unroll
                for (int rv = 0; rv < 4; ++rv) {
                    const int row = j * 16 + 4 * g + rv;
                    const int col = nt * 16 + m;
                    ldsu[row * 64 + (((col >> 3) ^ (row & 7)) << 3) + (col & 7)] = f2bf(acc[j][nt][rv] * 0.03125f);
                }
            }
    }
    __syncthreads();  // X complete; scratch dead; acc dead everywhere

    // ---- residual prefetch HERE (acc dead; MLP peak ~170+32 regs, fits) ----
    float xr[2][4][4];
#pragma unroll
    for (int mt = 0; mt < 2; ++mt)
#pragma unroll
        for (int nt = 0; nt < 4; ++nt)
#pragma unroll
            for (int rv = 0; rv < 4; ++rv)
                xr[mt][nt][rv] = xin[base + (size_t)((w + 4 * mt) * 16 + 4 * g + rv) * tmul + nt * 16 + m];

    // ---- Phase 3/4: MLP (bf16) in two 128-col hidden halves; H at ush 8192, stride 128 ----
    float b2v[4];
#pragma unroll
    for (int nt = 0; nt < 4; ++nt) b2v[nt] = b2[nt * 16 + m];
    f32x4 acc2[2][4];
#pragma unroll
    for (int mt = 0; mt < 2; ++mt)
#pragma unroll
        for (int nt = 0; nt < 4; ++nt) {
            f32x4 z = {b2v[nt], b2v[nt], b2v[nt], b2v[nt]};
            acc2[mt][nt] = z;
        }

#pragma unroll
    for (int half = 0; half < 2; ++half) {
        f32x4 acc1[8][2];
#pragma unroll
        for (int mt = 0; mt < 8; ++mt)
#pragma unroll
            for (int nt = 0; nt < 2; ++nt) {
                const float bv = half ? b1vb[nt] : b1va[nt];
                f32x4 z = {bv, bv, bv, bv};
                acc1[mt][nt] = z;
            }
        __builtin_amdgcn_s_setprio(1);
#pragma unroll
        for (int mt = 0; mt < 8; ++mt) {
            const int row = mt * 16 + m;
            const int c0 = (g ^ (row & 7)) << 3;
            bf16x8 a0 = *(const bf16x8*)&ldsu[row * 64 + c0];
            bf16x8 a1 = *(const bf16x8*)&ldsu[row * 64 + (c0 ^ 32)];
#pragma unroll
            for (int nt = 0; nt < 2; ++nt) {
                const bf16x8 w0f = half ? bw1b[nt][0] : bw1a[nt][0];
                const bf16x8 w1f = half ? bw1b[nt][1] : bw1a[nt][1];
                acc1[mt][nt] = __builtin_amdgcn_mfma_f32_16x16x32_bf16(a0, w0f, acc1[mt][nt], 0, 0, 0);
                acc1[mt][nt] = __builtin_amdgcn_mfma_f32_16x16x32_bf16(a1, w1f, acc1[mt][nt], 0, 0, 0);
            }
        }
        __builtin_amdgcn_s_setprio(0);
#pragma unroll
        for (int mt = 0; mt < 8; ++mt)
#pragma unroll
            for (int nt = 0; nt < 2; ++nt) {
                const int col = w * 32 + nt * 16 + m;
                const int c = col >> 3, jj = col & 7;
#pragma unroll
                for (int rv = 0; rv < 4; ++rv) {
                    const int row = mt * 16 + 4 * g + rv;
                    ldsu[8192 + row * 128 + ((c ^ (row & 7)) << 3) + jj] = f2bf(gelu_fast(acc1[mt][nt][rv]));
                }
            }
        __syncthreads();  // H half complete

        __builtin_amdgcn_s_setprio(1);
#pragma unroll
        for (int j = 0; j < 4; ++j) {
            bf16x8 aa[2];
#pragma unroll
            for (int mt = 0; mt < 2; ++mt) {
                const int row = (w + 4 * mt) * 16 + m;
                aa[mt] = *(const bf16x8*)&ldsu[8192 + row * 128 + (((4 * j + g) ^ (row & 7)) << 3)];
            }
#pragma unroll
            for (int nt = 0; nt < 4; ++nt) {
                const int row = nt * 16 + m;
                bf16x8 bfr = *(const bf16x8*)&w2t[row * 256 + half * 128 + (4 * j + g) * 8];
                acc2[0][nt] = __builtin_amdgcn_mfma_f32_16x16x32_bf16(aa[0], bfr, acc2[0][nt], 0, 0, 0);
                acc2[1][nt] = __builtin_amdgcn_mfma_f32_16x16x32_bf16(aa[1], bfr, acc2[1][nt], 0, 0, 0);
            }
        }
        __builtin_amdgcn_s_setprio(0);
        if (half == 0) __syncthreads();  // H region reused by half 1
    }

    // ---- store with prefetched residual ----
#pragma unroll
    for (int mt = 0; mt < 2; ++mt)
#pragma unroll
        for (int nt = 0; nt < 4; ++nt)
#pragma unroll
            for (int rv = 0; rv < 4; ++rv) {
                const int row = (w + 4 * mt) * 16 + 4 * g + rv;
                const int col = nt * 16 + m;
                const size_t xi = base + (size_t)row * tmul + col;
                xout[xi] = xr[mt][nt][rv] + acc2[mt][nt][rv];
            }
}

extern "C" void kernel_launch(void* const* d_in, const int* in_sizes, int n_in,
                              void* d_out, int out_size, void* d_ws, size_t ws_size,
                              hipStream_t stream) {
    const float* v         = (const float*)d_in[0];
    const float* gamma_row = (const float*)d_in[1];
    const float* beta_row  = (const float*)d_in[2];
    const float* gamma_col = (const float*)d_in[3];
    const float* beta_col  = (const float*)d_in[4];
    const float* mp_row    = (const float*)d_in[5];
    const float* mm_row    = (const float*)d_in[6];
    const float* mp_col    = (const float*)d_in[7];
    const float* mm_col    = (const float*)d_in[8];
    const float* w1_row    = (const float*)d_in[9];
    const float* b1_row    = (const float*)d_in[10];
    const float* w2_row    = (const float*)d_in[11];
    const float* b2_row    = (const float*)d_in[12];
    const float* w1_col    = (const float*)d_in[13];
    const float* b1_col    = (const float*)d_in[14];
    const float* w2_col    = (const float*)d_in[15];
    const float* b2_col    = (const float*)d_in[16];
    const float* phi_row   = (const float*)d_in[17];
    const float* phi_col   = (const float*)d_in[18];
    float* out = (float*)d_out;
    char* ws   = (char*)d_ws;

    unsigned char* GfR   = (unsigned char*)ws;                       // 512 KB
    unsigned char* GfC   = (unsigned char*)(ws + (1u << 20));        // 512 KB
    unsigned short* w1tR = (unsigned short*)(ws + (2u << 20));
    unsigned short* w2tR = (unsigned short*)(ws + (2u << 20) + 32768);
    unsigned short* w1tC = (unsigned short*)(ws + (2u << 20) + 65536);
    unsigned short* w2tC = (unsigned short*)(ws + (2u << 20) + 98304);

    init_kernel<<<260, 256, 0, stream>>>(phi_row, mp_row, mm_row, GfR,
                                         phi_col, mp_col, mm_col, GfC,
                                         w1_row, w1_col, w2_row, w2_col,
                                         w1tR, w1tC, w2tR, w2tC);

    // row pass: seq=(b,h), rmul=8192 (h stride), tmul=64 (w stride)
    fused_kernel<<<512, 256, 0, stream>>>(v, out, GfR, w1tR, w2tR, b1_row, b2_row,
                                          gamma_row, beta_row, 8192, 64);
    // col pass: seq=(b,w), rmul=64 (w stride), tmul=8192 (h stride)
    fused_kernel<<<512, 256, 0, stream>>>(out, out, GfC, w1tC, w2tC, b1_col, b2_col,
                                          gamma_col, beta_col, 64, 8192);
}

// Round 19
// 100.007 us; speedup vs baseline: 1.5426x; 1.1603x over previous
//
#include <hip/hip_runtime.h>
#include <hip/hip_fp8.h>

typedef __attribute__((ext_vector_type(8))) short bf16x8;
typedef __attribute__((ext_vector_type(4))) float f32x4;
typedef __attribute__((ext_vector_type(8))) int i32x8;
typedef __attribute__((ext_vector_type(4))) unsigned int u32x4;

__device__ __forceinline__ float gelu_fast(float x) {
    const float u = 0.7978845608028654f * x * (1.0f + 0.044715f * x * x);
    return x * __builtin_amdgcn_rcpf(1.0f + __expf(-2.0f * u));
}

__device__ __forceinline__ unsigned short f2bf(float x) {
    union { float f; unsigned int u; } v; v.f = x;
    unsigned int r = v.u + 0x7FFF + ((v.u >> 16) & 1);
    return (unsigned short)(r >> 16);
}

__device__ __forceinline__ unsigned char f2fp8(float x) {
    __hip_fp8_e4m3 h(x);  // OCP e4m3fn, saturating
    return *(unsigned char*)&h;
}

// blocks [0,256): Gf8 production, K=128 pair-merged fragment-major:
//   Gf8[sp][nt][lane=m+16g][32B]: lane holds col e=nt*16+m, k=32g..32g+31 where
//   k<64 -> slice s=2sp d=k;  k>=64 -> slice s=2sp+1 d=k-64.  value = fp8(32*Gc[s][d][e]).
// blocks [256,260): weight transposes (bf16).
__global__ __launch_bounds__(256) void init_kernel(const float* __restrict__ phi_r, const float* __restrict__ mp_r,
                                                   const float* __restrict__ mm_r, unsigned char* __restrict__ GfR,
                                                   const float* __restrict__ phi_c, const float* __restrict__ mp_c,
                                                   const float* __restrict__ mm_c, unsigned char* __restrict__ GfC,
                                                   const float* __restrict__ w1r, const float* __restrict__ w1c,
                                                   const float* __restrict__ w2r, const float* __restrict__ w2c,
                                                   unsigned short* __restrict__ w1tr, unsigned short* __restrict__ w1tc,
                                                   unsigned short* __restrict__ w2tr, unsigned short* __restrict__ w2tc) {
    const int bid = blockIdx.x, tid = threadIdx.x;
    __shared__ float phis[256];
    __shared__ unsigned char tile8[4096];  // 16 s x 256 fp8 (e-major, d-minor)
    if (bid < 256) {
        const int side = bid >> 7, rem = bid & 127;
        const int chunk = rem >> 3, s0 = (rem & 7) * 16;
        const float* phi = side ? phi_c : phi_r;
        const float* mp  = side ? mp_c  : mp_r;
        const float* mm  = side ? mm_c  : mm_r;
        unsigned char* Gf8 = side ? GfC : GfR;
        const int i = chunk * 256 + tid;
        float pe[16], po[16];
#pragma unroll
        for (int k = 0; k < 16; ++k) {
            const float a = mp[k * 4096 + i];
            const float b = mm[k * 4096 + i];
            pe[k] = a + b; po[k] = a - b;
        }
        phis[tid] = phi[s0 * 16 + tid];
        __syncthreads();
        const int e = tid & 63, dl = tid >> 6;
        const int d0 = chunk * 4;
#pragma unroll
        for (int sb = 0; sb < 16; ++sb) {
            const int s = s0 + sb;
            const float* pk = &phis[sb * 16];
            float acc = 0.0f;
            if (s & 1) {
#pragma unroll
                for (int k = 0; k < 16; ++k) acc += pk[k] * po[k];
            } else {
#pragma unroll
                for (int k = 0; k < 16; ++k) acc += pk[k] * pe[k];
            }
            tile8[sb * 256 + e * 4 + dl] = f2fp8(acc * 32.0f);
        }
        __syncthreads();
#pragma unroll
        for (int it = 0; it < 4; ++it) {
            const int p = it * 256 + tid;
            const int sb = p >> 6, ee = p & 63;
            unsigned int v = *(const unsigned int*)&tile8[sb * 256 + ee * 4];
            const int s = s0 + sb;
            const int sp = s >> 1, hi = s & 1;
            const int k0 = 64 * hi + d0;          // d0..d0+3 consecutive k
            const int gg = k0 >> 5, kk0 = k0 & 31;
            *(unsigned int*)&Gf8[(size_t)sp * 8192 + (ee >> 4) * 2048 +
                                 ((ee & 15) + 16 * gg) * 32 + kk0] = v;
        }
    } else {
        const int b = bid - 256;
        if (b < 2) {
            const float* w1 = b ? w1c : w1r;
            unsigned short* dst = b ? w1tc : w1tr;
            const int n = tid;
            for (int k = 0; k < 64; ++k) dst[n * 64 + k] = f2bf(w1[k * 256 + n]);
        } else {
            const float* w2 = (b == 3) ? w2c : w2r;
            unsigned short* dst = (b == 3) ? w2tc : w2tr;
            const int n = tid & 63, kq = tid >> 6;
            for (int kk2 = 0; kk2 < 64; ++kk2) {
                const int k = kq * 64 + kk2;
                dst[n * 256 + k] = f2bf(w2[k * 64 + n]);
            }
        }
    }
}

// Fused pass: fp8 spec via MX K=128 s-pair MFMAs (scales = 1.0), bf16 MLP.
// 1 seq/block, 4 waves, grid 512 (2 blocks/CU). 50 KB LDS.
// Wave w handles s-pairs sp = 4r + w, r=0..15 (2 taps per MFMA, jmin shared per pair).
// ys fp8 rows 64 B, swizzled in 16-B chunks: chunk c stored at c ^ (row&3).
// REGISTER LEDGER (2 waves/SIMD => 256/wave): acc(128) + Ba/Bb(64) + misc ~60 = ~252.
// min-waves stays 2 (R10: (256,3) caps ~85 -> spills). xr prefetch post-T6 only (R13).
// LDS bytes: ys [0,10240) | scrA [18432,34816) scrB [34816,51200) | X [0,16384) | H [16384,49152)
#define SPEC_BODY(RR, BC, BN)                                                        \
    {                                                                                \
        const int sp_ = 4 * (RR) + w;                                                \
        if ((RR) < 15) {                                                             \
            const unsigned char* gq = Gf8 + (size_t)(sp_ + 4) * 8192 + lane * 32;    \
            _Pragma("unroll")                                                        \
            for (int f = 0; f < 4; ++f) BN[f] = *(const i32x8*)(gq + f * 2048);      \
        }                                                                            \
        const int jmin_ = __builtin_amdgcn_readfirstlane((2 * sp_ + 1) >> 4);        \
        __builtin_amdgcn_s_setprio(1);                                               \
        _Pragma("unroll")                                                            \
        for (int j = 0; j < 8; ++j) {                                                \
            if (j >= jmin_) {                                                        \
                const int srow = 16 + 16 * j - 2 * sp_ - (g >> 1) + m;               \
                const int cb_ = 2 * (g & 1);                                         \
                u32x4 lo_ = *(const u32x4*)&lds8[srow * 64 + ((cb_ ^ (srow & 3)) << 4)];       \
                u32x4 hi_ = *(const u32x4*)&lds8[srow * 64 + (((cb_ + 1) ^ (srow & 3)) << 4)]; \
                i32x8 av;                                                            \
                av[0] = lo_[0]; av[1] = lo_[1]; av[2] = lo_[2]; av[3] = lo_[3];      \
                av[4] = hi_[0]; av[5] = hi_[1]; av[6] = hi_[2]; av[7] = hi_[3];      \
                _Pragma("unroll")                                                    \
                for (int nt = 0; nt < 4; ++nt)                                       \
                    acc[j][nt] = __builtin_amdgcn_mfma_scale_f32_16x16x128_f8f6f4(   \
                        av, BC[nt], acc[j][nt], 0, 0, 0, 0x7F7F7F7F, 0, 0x7F7F7F7F); \
            }                                                                        \
        }                                                                            \
        __builtin_amdgcn_s_setprio(0);                                               \
    }

__global__ __launch_bounds__(256, 2) void fused_kernel(const float* __restrict__ xin,
                                                       float* __restrict__ xout,
                                                       const unsigned char* __restrict__ Gf8,
                                                       const unsigned short* __restrict__ w1t,
                                                       const unsigned short* __restrict__ w2t,
                                                       const float* __restrict__ b1,
                                                       const float* __restrict__ b2,
                                                       const float* __restrict__ gamma,
                                                       const float* __restrict__ beta,
                                                       int rmul, int tmul) {
    __shared__ unsigned char lds8[51200];  // 50 KB
    unsigned short* const ldsu = (unsigned short*)lds8;  // bf16 view for X/H
    const int tid = threadIdx.x;
    const int w = tid >> 6, lane = tid & 63;
    const int seq = blockIdx.x;
    const int m = lane & 15, g = lane >> 4;
    const int bb = seq >> 7, rr = seq & 127;
    const size_t base = (size_t)bb * 1048576 + (size_t)rr * (size_t)rmul;

    // zero ys prefix rows 0..15 (bytes [0,1024))
    *(unsigned int*)&lds8[tid * 4] = 0u;

    // round-0 B prefetch (hides L2 latency under LN)
    i32x8 Ba[4], Bb[4];
    {
        const unsigned char* gq = Gf8 + (size_t)w * 8192 + lane * 32;
#pragma unroll
        for (int f = 0; f < 4; ++f) Ba[f] = *(const i32x8*)(gq + f * 2048);
    }

    // ---- Phase 0: LayerNorm rows w*32 .. w*32+31 into fp8 ys (16-B chunk swizzle) ----
    {
        const float gl = gamma[lane], bl = beta[lane];
        float xv[32];
#pragma unroll
        for (int ti = 0; ti < 32; ++ti)
            xv[ti] = xin[base + (size_t)(w * 32 + ti) * tmul + lane];
#pragma unroll
        for (int ti = 0; ti < 32; ++ti) {
            const int t = w * 32 + ti;
            float s1 = xv[ti];
#pragma unroll
            for (int mm2 = 32; mm2 >= 1; mm2 >>= 1) s1 += __shfl_xor(s1, mm2);
            const float mu = s1 * (1.0f / 64.0f);
            const float dv = xv[ti] - mu;
            float s2 = dv * dv;
#pragma unroll
            for (int mm2 = 32; mm2 >= 1; mm2 >>= 1) s2 += __shfl_xor(s2, mm2);
            const float rstd = rsqrtf(s2 * (1.0f / 64.0f) + 1e-5f);
            const float nv = dv * rstd * gl + bl;
            lds8[(t + 16) * 64 + (((lane >> 4) ^ (t & 3)) << 4) + (lane & 15)] = f2fp8(nv);
        }
    }
    __syncthreads();  // ys complete

    // ---- Phase 1: spec main loop (no barriers), 16 rounds of s-pairs ----
    f32x4 acc[8][4];
#pragma unroll
    for (int j = 0; j < 8; ++j)
#pragma unroll
        for (int nt = 0; nt < 4; ++nt) {
            f32x4 z = {0.0f, 0.0f, 0.0f, 0.0f};
            acc[j][nt] = z;
        }
    for (int rp = 0; rp < 8; ++rp) {
        SPEC_BODY(2 * rp,     Ba, Bb);
        SPEC_BODY(2 * rp + 1, Bb, Ba);
    }

    // ---- Phase 2: pairwise tree reduction (32 KB scratch) ----
    char* const scrA = (char*)lds8 + 18432;
    char* const scrB = (char*)lds8 + 34816;
    if (w == 1 || w == 3) {
        char* pb = (w == 1 ? scrA : scrB) + lane * 16;
#pragma unroll
        for (int j = 0; j < 4; ++j)
#pragma unroll
            for (int nt = 0; nt < 4; ++nt)
                *(f32x4*)(pb + (j * 4 + nt) * 1024) = acc[j][nt];
    }
    // weight fragment loads (overlap reduction); wave owns hidden cols [32w,32w+32) per half
    bf16x8 bw1a[2][2], bw1b[2][2];
    float b1va[2], b1vb[2];
#pragma unroll
    for (int nt = 0; nt < 2; ++nt) {
        const int col0 = w * 32 + nt * 16 + m;
#pragma unroll
        for (int j = 0; j < 2; ++j) {
            bw1a[nt][j] = *(const bf16x8*)&w1t[col0 * 64 + (4 * j + g) * 8];
            bw1b[nt][j] = *(const bf16x8*)&w1t[(128 + col0) * 64 + (4 * j + g) * 8];
        }
        b1va[nt] = b1[col0];
        b1vb[nt] = b1[128 + col0];
    }
    __syncthreads();
    if (w == 0 || w == 2) {
        const char* pb = (w == 0 ? scrA : scrB) + lane * 16;
#pragma unroll
        for (int j = 0; j < 4; ++j)
#pragma unroll
            for (int nt = 0; nt < 4; ++nt)
                acc[j][nt] += *(const f32x4*)(pb + (j * 4 + nt) * 1024);
    }
    __syncthreads();
    if (w == 1 || w == 3) {
        char* pb = (w == 1 ? scrA : scrB) + lane * 16;
#pragma unroll
        for (int j = 4; j < 8; ++j)
#pragma unroll
            for (int nt = 0; nt < 4; ++nt)
                *(f32x4*)(pb + ((j - 4) * 4 + nt) * 1024) = acc[j][nt];
    }
    __syncthreads();
    if (w == 0 || w == 2) {
        const char* pb = (w == 0 ? scrA : scrB) + lane * 16;
#pragma unroll
        for (int j = 4; j < 8; ++j)
#pragma unroll
            for (int nt = 0; nt < 4; ++nt)
                acc[j][nt] += *(const f32x4*)(pb + ((j - 4) * 4 + nt) * 1024);
        if (w == 0) {
#pragma unroll
            for (int j = 4; j < 8; ++j)
#pragma unroll
                for (int nt = 0; nt < 4; ++nt)
                    *(f32x4*)(scrA + ((j - 4) * 4 + nt) * 1024 + lane * 16) = acc[j][nt];
        } else {
#pragma unroll
            for (int j = 0; j < 4; ++j)
#pragma unroll
                for (int nt = 0; nt < 4; ++nt)
                    *(f32x4*)(scrB + (j * 4 + nt) * 1024 + lane * 16) = acc[j][nt];
        }
    }
    __syncthreads();
    // T6: finalize -> X bf16 (acc carries 32x scale; undo here)
    if (w == 0) {
#pragma unroll
        for (int j = 0; j < 4; ++j)
#pragma unroll
            for (int nt = 0; nt < 4; ++nt) {
                acc[j][nt] += *(const f32x4*)(scrB + (j * 4 + nt) * 1024 + lane * 16);
#pragma unroll
                for (int rv = 0; rv < 4; ++rv) {
                    const int row = j * 16 + 4 * g + rv;
                    const int col = nt * 16 + m;
                    ldsu[row * 64 + (((col >> 3) ^ (row & 7)) << 3) + (col & 7)] = f2bf(acc[j][nt][rv] * 0.03125f);
                }
            }
    } else if (w == 2) {
#pragma unroll
        for (int j = 4; j < 8; ++j)
#pragma unroll
            for (int nt = 0; nt < 4; ++nt) {
                acc[j][nt] += *(const f32x4*)(scrA + ((j - 4) * 4 + nt) * 1024 + lane * 16);
#pragma unroll
                for (int rv = 0; rv < 4; ++rv) {
                    const int row = j * 16 + 4 * g + rv;
                    const int col = nt * 16 + m;
                    ldsu[row * 64 + (((col >> 3) ^ (row & 7)) << 3) + (col & 7)] = f2bf(acc[j][nt][rv] * 0.03125f);
                }
            }
    }
    __syncthreads();  // X complete; scratch dead; acc dead everywhere

    // ---- residual prefetch HERE (acc dead; MLP peak ~170+32 regs, fits) ----
    float xr[2][4][4];
#pragma unroll
    for (int mt = 0; mt < 2; ++mt)
#pragma unroll
        for (int nt = 0; nt < 4; ++nt)
#pragma unroll
            for (int rv = 0; rv < 4; ++rv)
                xr[mt][nt][rv] = xin[base + (size_t)((w + 4 * mt) * 16 + 4 * g + rv) * tmul + nt * 16 + m];

    // ---- Phase 3/4: MLP (bf16) in two 128-col hidden halves; H at ush 8192, stride 128 ----
    float b2v[4];
#pragma unroll
    for (int nt = 0; nt < 4; ++nt) b2v[nt] = b2[nt * 16 + m];
    f32x4 acc2[2][4];
#pragma unroll
    for (int mt = 0; mt < 2; ++mt)
#pragma unroll
        for (int nt = 0; nt < 4; ++nt) {
            f32x4 z = {b2v[nt], b2v[nt], b2v[nt], b2v[nt]};
            acc2[mt][nt] = z;
        }

#pragma unroll
    for (int half = 0; half < 2; ++half) {
        f32x4 acc1[8][2];
#pragma unroll
        for (int mt = 0; mt < 8; ++mt)
#pragma unroll
            for (int nt = 0; nt < 2; ++nt) {
                const float bv = half ? b1vb[nt] : b1va[nt];
                f32x4 z = {bv, bv, bv, bv};
                acc1[mt][nt] = z;
            }
        __builtin_amdgcn_s_setprio(1);
#pragma unroll
        for (int mt = 0; mt < 8; ++mt) {
            const int row = mt * 16 + m;
            const int c0 = (g ^ (row & 7)) << 3;
            bf16x8 a0 = *(const bf16x8*)&ldsu[row * 64 + c0];
            bf16x8 a1 = *(const bf16x8*)&ldsu[row * 64 + (c0 ^ 32)];
#pragma unroll
            for (int nt = 0; nt < 2; ++nt) {
                const bf16x8 w0f = half ? bw1b[nt][0] : bw1a[nt][0];
                const bf16x8 w1f = half ? bw1b[nt][1] : bw1a[nt][1];
                acc1[mt][nt] = __builtin_amdgcn_mfma_f32_16x16x32_bf16(a0, w0f, acc1[mt][nt], 0, 0, 0);
                acc1[mt][nt] = __builtin_amdgcn_mfma_f32_16x16x32_bf16(a1, w1f, acc1[mt][nt], 0, 0, 0);
            }
        }
        __builtin_amdgcn_s_setprio(0);
#pragma unroll
        for (int mt = 0; mt < 8; ++mt)
#pragma unroll
            for (int nt = 0; nt < 2; ++nt) {
                const int col = w * 32 + nt * 16 + m;
                const int c = col >> 3, jj = col & 7;
#pragma unroll
                for (int rv = 0; rv < 4; ++rv) {
                    const int row = mt * 16 + 4 * g + rv;
                    ldsu[8192 + row * 128 + ((c ^ (row & 7)) << 3) + jj] = f2bf(gelu_fast(acc1[mt][nt][rv]));
                }
            }
        __syncthreads();  // H half complete

        __builtin_amdgcn_s_setprio(1);
#pragma unroll
        for (int j = 0; j < 4; ++j) {
            bf16x8 aa[2];
#pragma unroll
            for (int mt = 0; mt < 2; ++mt) {
                const int row = (w + 4 * mt) * 16 + m;
                aa[mt] = *(const bf16x8*)&ldsu[8192 + row * 128 + (((4 * j + g) ^ (row & 7)) << 3)];
            }
#pragma unroll
            for (int nt = 0; nt < 4; ++nt) {
                const int row = nt * 16 + m;
                bf16x8 bfr = *(const bf16x8*)&w2t[row * 256 + half * 128 + (4 * j + g) * 8];
                acc2[0][nt] = __builtin_amdgcn_mfma_f32_16x16x32_bf16(aa[0], bfr, acc2[0][nt], 0, 0, 0);
                acc2[1][nt] = __builtin_amdgcn_mfma_f32_16x16x32_bf16(aa[1], bfr, acc2[1][nt], 0, 0, 0);
            }
        }
        __builtin_amdgcn_s_setprio(0);
        if (half == 0) __syncthreads();  // H region reused by half 1
    }

    // ---- store with prefetched residual ----
#pragma unroll
    for (int mt = 0; mt < 2; ++mt)
#pragma unroll
        for (int nt = 0; nt < 4; ++nt)
#pragma unroll
            for (int rv = 0; rv < 4; ++rv) {
                const int row = (w + 4 * mt) * 16 + 4 * g + rv;
                const int col = nt * 16 + m;
                const size_t xi = base + (size_t)row * tmul + col;
                xout[xi] = xr[mt][nt][rv] + acc2[mt][nt][rv];
            }
}

extern "C" void kernel_launch(void* const* d_in, const int* in_sizes, int n_in,
                              void* d_out, int out_size, void* d_ws, size_t ws_size,
                              hipStream_t stream) {
    const float* v         = (const float*)d_in[0];
    const float* gamma_row = (const float*)d_in[1];
    const float* beta_row  = (const float*)d_in[2];
    const float* gamma_col = (const float*)d_in[3];
    const float* beta_col  = (const float*)d_in[4];
    const float* mp_row    = (const float*)d_in[5];
    const float* mm_row    = (const float*)d_in[6];
    const float* mp_col    = (const float*)d_in[7];
    const float* mm_col    = (const float*)d_in[8];
    const float* w1_row    = (const float*)d_in[9];
    const float* b1_row    = (const float*)d_in[10];
    const float* w2_row    = (const float*)d_in[11];
    const float* b2_row    = (const float*)d_in[12];
    const float* w1_col    = (const float*)d_in[13];
    const float* b1_col    = (const float*)d_in[14];
    const float* w2_col    = (const float*)d_in[15];
    const float* b2_col    = (const float*)d_in[16];
    const float* phi_row   = (const float*)d_in[17];
    const float* phi_col   = (const float*)d_in[18];
    float* out = (float*)d_out;
    char* ws   = (char*)d_ws;

    unsigned char* GfR   = (unsigned char*)ws;                       // 512 KB
    unsigned char* GfC   = (unsigned char*)(ws + (1u << 20));        // 512 KB
    unsigned short* w1tR = (unsigned short*)(ws + (2u << 20));
    unsigned short* w2tR = (unsigned short*)(ws + (2u << 20) + 32768);
    unsigned short* w1tC = (unsigned short*)(ws + (2u << 20) + 65536);
    unsigned short* w2tC = (unsigned short*)(ws + (2u << 20) + 98304);

    init_kernel<<<260, 256, 0, stream>>>(phi_row, mp_row, mm_row, GfR,
                                         phi_col, mp_col, mm_col, GfC,
                                         w1_row, w1_col, w2_row, w2_col,
                                         w1tR, w1tC, w2tR, w2tC);

    // row pass: seq=(b,h), rmul=8192 (h stride), tmul=64 (w stride)
    fused_kernel<<<512, 256, 0, stream>>>(v, out, GfR, w1tR, w2tR, b1_row, b2_row,
                                          gamma_row, beta_row, 8192, 64);
    // col pass: seq=(b,w), rmul=64 (w stride), tmul=8192 (h stride)
    fused_kernel<<<512, 256, 0, stream>>>(out, out, GfC, w1tC, w2tC, b1_col, b2_col,
                                          gamma_col, beta_col, 64, 8192);
}